// Round 4
// baseline (395.855 us; speedup 1.0000x reference)
//
#include <hip/hip_runtime.h>
#include <math.h>

#define BB   64
#define HWP  1024
#define SS   512
#define DD   256
#define TAU_INV (1.0f/0.07f)
#define SIGMA   (1.0f/1024.0f)

typedef unsigned short us;
typedef __attribute__((ext_vector_type(8))) short short8v;
typedef __attribute__((ext_vector_type(8))) unsigned short ushort8v;
typedef __attribute__((ext_vector_type(4))) float floatx4;

__device__ __forceinline__ float bf2f(us u) {
    return __uint_as_float((unsigned)u << 16);
}
__device__ __forceinline__ us f2bf(float f) {
    unsigned u = __float_as_uint(f);
    u += 0x7FFFu + ((u >> 16) & 1u);
    return (us)(u >> 16);
}
__device__ __forceinline__ void split_bf(float v, us& h, us& l) {
    h = f2bf(v);
    l = f2bf(v - bf2f(h));
}

__global__ void zero_out_k(float* out) { if (threadIdx.x == 0) out[0] = 0.0f; }

// =====================  MFMA GEMM  =====================
// C[m,n] = sum_k A(m,k)*B(n,k). Tile 128 x NT, BK=32, 16x16x32 bf16 MFMA.
// R11-R13 (prefetch depth / raw barriers / 8-wave occupancy) were all NULL on
// G6: VALUBusy 37-41%, MfmaUtil ~12%, dur ~57us invariant. The bound is the
// staging ISSUE VOLUME: COL modes did 16 scalar 2B VMEM loads + 16 addr calcs
// per thread per k-step (8x the data's instruction need).
// R14: COL staging (NW==8) rewritten — ONE ushort8v load per thread along the
// contiguous m-axis (k=tid>>4, m=(tid&15)*8), then LDS-transpose via 8
// ds_write_b16 with immediate offsets. Transposed writes chunk-XOR-swizzled
// (k-chunk ^= (m>>3)&3): 16-way bank conflict -> 4-way, reads stay b128/16B
// aligned with the matching XOR. VMEM insts/k-step: 16 -> 2.
enum { OPM_F32_ROW = 0, OPM_F32_COL = 1, OPM_SPL_ROW = 2, OPM_SPL_COL = 3,
       OPM_B16_COL = 4, OPM_B16_ROW = 5, OPM_WGT_COL = 6 };
enum { OUT_F32 = 0, OUT_B16 = 1 };

#define LDSTRIDE 40

template<int MODE, int ROWS, int NW>
struct SRegs {
    static constexpr int RR = ROWS / 128;
    static constexpr bool ISF32 = (MODE == OPM_F32_ROW) || (MODE == OPM_F32_COL);
    ushort8v h[ISF32 ? 1 : RR][2];     // NW==8 paths use [rr][0] only (DCE'd)
    ushort8v l[(MODE == OPM_SPL_ROW) ? RR : 1][2];
    float4   f[ISF32 ? RR : 1][4];
};

// global -> registers (raw data, no conversion math)
template<int MODE, int ROWS, int NW>
__device__ __forceinline__ void stage_load(
    const char* p0, const char* p1, int ld, int row0, int k0, int tid,
    SRegs<MODE, ROWS, NW>& R)
{
    #pragma unroll
    for (int rr = 0; rr < ROWS / 128; ++rr) {
        if constexpr (MODE == OPM_SPL_ROW) {
            // NW==4 only
            const us* ph = (const us*)p0;
            const us* pl = (const us*)p1;
            const int i = rr * 128 + (tid >> 1), ko = (tid & 1) * 16;
            const long long g = (long long)(row0 + i) * ld + k0 + ko;
            R.h[rr][0] = *(const ushort8v*)&ph[g];
            R.h[rr][1] = *(const ushort8v*)&ph[g + 8];
            R.l[rr][0] = *(const ushort8v*)&pl[g];
            R.l[rr][1] = *(const ushort8v*)&pl[g + 8];
        } else if constexpr (MODE == OPM_B16_ROW) {
            const us* ph = (const us*)p0;
            if constexpr (NW == 4) {
                const int i = rr * 128 + (tid >> 1), ko = (tid & 1) * 16;
                const long long g = (long long)(row0 + i) * ld + k0 + ko;
                R.h[rr][0] = *(const ushort8v*)&ph[g];
                R.h[rr][1] = *(const ushort8v*)&ph[g + 8];
            } else {
                const int i = rr * 128 + (tid >> 2), ko = (tid & 3) * 8;
                const long long g = (long long)(row0 + i) * ld + k0 + ko;
                R.h[rr][0] = *(const ushort8v*)&ph[g];
            }
        } else if constexpr (MODE == OPM_F32_ROW) {
            // NW==4 only
            const float* pf = (const float*)p0;
            const int i = rr * 128 + (tid >> 1), ko = (tid & 1) * 16;
            const long long g = (long long)(row0 + i) * ld + k0 + ko;
            #pragma unroll
            for (int c = 0; c < 4; ++c)
                R.f[rr][c] = *(const float4*)&pf[g + c * 4];
        } else if constexpr (MODE == OPM_F32_COL) {
            // NW==4 only (G1)
            const float* pf = (const float*)p0;
            const int m = rr * 128 + (tid & 127), kh = (tid >> 7) * 16;
            const long long base = (long long)(k0 + kh) * ld + row0 + m;
            #pragma unroll
            for (int c = 0; c < 4; ++c) {
                float4 v;
                v.x = pf[base + (long long)(c * 4 + 0) * ld];
                v.y = pf[base + (long long)(c * 4 + 1) * ld];
                v.z = pf[base + (long long)(c * 4 + 2) * ld];
                v.w = pf[base + (long long)(c * 4 + 3) * ld];
                R.f[rr][c] = v;
            }
        } else {  // OPM_B16_COL, OPM_WGT_COL
            const us* ph = (const us*)p0;
            if constexpr (NW == 4) {
                const int m = rr * 128 + (tid & 127), kh = (tid >> 7) * 16;
                const long long base = (long long)(k0 + kh) * ld + row0 + m;
                #pragma unroll
                for (int kk = 0; kk < 8; ++kk) {
                    R.h[rr][0][kk] = ph[base + (long long)kk * ld];
                    R.h[rr][1][kk] = ph[base + (long long)(kk + 8) * ld];
                }
            } else {
                // R14: ONE wide load along contiguous m for a fixed k.
                // k = tid>>4 (0..31), m = (tid&15)*8 (0..120): 512thr x 8 = 128x32.
                const int k_idx = tid >> 4, m_off = (tid & 15) * 8;
                const long long g = (long long)(k0 + k_idx) * ld + row0 + m_off;
                R.h[rr][0] = *(const ushort8v*)&ph[g];
            }
        }
    }
}

// registers -> LDS (conversion / weight math happens here)
template<int MODE, int ROWS, int NW>
__device__ __forceinline__ void stage_store(
    const SRegs<MODE, ROWS, NW>& R, us* ldsH, us* ldsL, int tid,
    const float* nlo, const float* inv)
{
    #pragma unroll
    for (int rr = 0; rr < ROWS / 128; ++rr) {
        if constexpr (MODE == OPM_SPL_ROW) {
            const int i = rr * 128 + (tid >> 1), ko = (tid & 1) * 16;
            *(ushort8v*)&ldsH[i * LDSTRIDE + ko]     = R.h[rr][0];
            *(ushort8v*)&ldsH[i * LDSTRIDE + ko + 8] = R.h[rr][1];
            *(ushort8v*)&ldsL[i * LDSTRIDE + ko]     = R.l[rr][0];
            *(ushort8v*)&ldsL[i * LDSTRIDE + ko + 8] = R.l[rr][1];
        } else if constexpr (MODE == OPM_B16_ROW) {
            if constexpr (NW == 4) {
                const int i = rr * 128 + (tid >> 1), ko = (tid & 1) * 16;
                *(ushort8v*)&ldsH[i * LDSTRIDE + ko]     = R.h[rr][0];
                *(ushort8v*)&ldsH[i * LDSTRIDE + ko + 8] = R.h[rr][1];
            } else {
                const int i = rr * 128 + (tid >> 2), ko = (tid & 3) * 8;
                *(ushort8v*)&ldsH[i * LDSTRIDE + ko] = R.h[rr][0];
            }
        } else if constexpr (MODE == OPM_F32_ROW) {
            const int i = rr * 128 + (tid >> 1), ko = (tid & 1) * 16;
            us h16[16], l16a[16];
            #pragma unroll
            for (int c = 0; c < 4; ++c) {
                float4 v = R.f[rr][c];
                split_bf(v.x, h16[c*4+0], l16a[c*4+0]);
                split_bf(v.y, h16[c*4+1], l16a[c*4+1]);
                split_bf(v.z, h16[c*4+2], l16a[c*4+2]);
                split_bf(v.w, h16[c*4+3], l16a[c*4+3]);
            }
            *(ushort8v*)&ldsH[i * LDSTRIDE + ko]     = *(const ushort8v*)&h16[0];
            *(ushort8v*)&ldsH[i * LDSTRIDE + ko + 8] = *(const ushort8v*)&h16[8];
            *(ushort8v*)&ldsL[i * LDSTRIDE + ko]     = *(const ushort8v*)&l16a[0];
            *(ushort8v*)&ldsL[i * LDSTRIDE + ko + 8] = *(const ushort8v*)&l16a[8];
        } else if constexpr (MODE == OPM_F32_COL) {
            const int m = rr * 128 + (tid & 127), kh = (tid >> 7) * 16;
            us vh[16], vl[16];
            #pragma unroll
            for (int c = 0; c < 4; ++c) {
                float4 v = R.f[rr][c];
                split_bf(v.x, vh[c*4+0], vl[c*4+0]);
                split_bf(v.y, vh[c*4+1], vl[c*4+1]);
                split_bf(v.z, vh[c*4+2], vl[c*4+2]);
                split_bf(v.w, vh[c*4+3], vl[c*4+3]);
            }
            *(ushort8v*)&ldsH[m * LDSTRIDE + kh]     = *(const ushort8v*)&vh[0];
            *(ushort8v*)&ldsH[m * LDSTRIDE + kh + 8] = *(const ushort8v*)&vh[8];
            *(ushort8v*)&ldsL[m * LDSTRIDE + kh]     = *(const ushort8v*)&vl[0];
            *(ushort8v*)&ldsL[m * LDSTRIDE + kh + 8] = *(const ushort8v*)&vl[8];
        } else if constexpr (MODE == OPM_B16_COL || MODE == OPM_WGT_COL) {
            if constexpr (NW == 4) {
                const int m = rr * 128 + (tid & 127), kh = (tid >> 7) * 16;
                us v[16];
                #pragma unroll
                for (int kk = 0; kk < 16; ++kk) {
                    us raw = (kk < 8) ? R.h[rr][0][kk & 7] : R.h[rr][1][kk & 7];
                    if constexpr (MODE == OPM_WGT_COL) {
                        const float w0 = fmaf(bf2f(raw), inv[0], nlo[0]);
                        raw = (w0 < SIGMA) ? (us)0 : f2bf(w0);
                    }
                    v[kk] = raw;
                }
                *(ushort8v*)&ldsH[m * LDSTRIDE + kh]     = *(const ushort8v*)&v[0];
                *(ushort8v*)&ldsH[m * LDSTRIDE + kh + 8] = *(const ushort8v*)&v[8];
            } else {
                // R14: transposed scatter into [m][k] layout, 8 ds_write_b16
                // with immediate offsets (j*LDSTRIDE). k-chunk XOR-swizzled by
                // (m>>3)&3 == tid&3 -> write conflicts 16-way -> 4-way.
                const int k_idx = tid >> 4;
                const int m_base = (tid & 15) * 8;
                const int chunk = (k_idx >> 3) ^ (tid & 3);
                us* bp = &ldsH[m_base * LDSTRIDE + chunk * 8 + (k_idx & 7)];
                #pragma unroll
                for (int j = 0; j < 8; ++j) {
                    us v = R.h[rr][0][j];
                    if constexpr (MODE == OPM_WGT_COL) {
                        const float w0 = fmaf(bf2f(v), inv[j], nlo[j]);
                        v = (w0 < SIGMA) ? (us)0 : f2bf(w0);
                    }
                    bp[j * LDSTRIDE] = v;
                }
            }
        }
    }
}

template<int AMODE, int BMODE, int OMODE, int EPI, int NT, int PREF, int NW>
__global__ __launch_bounds__(NW * 64) void mfma_gemm(
    const void* A0, const void* A1, const void* B0, const void* B1, void* C0,
    int M, int N, int K, int lda, int ldb, int ldc,
    long long sA, long long sB, long long sC,
    const float* __restrict__ bias, const float* __restrict__ invm,
    const float* __restrict__ invn, float scale,
    const float* __restrict__ wlo, const float* __restrict__ whi,
    float* __restrict__ aux0, float* __restrict__ aux1,
    float* __restrict__ aux2, float* __restrict__ aux3, float* __restrict__ aux4)
{
    constexpr bool ASPL = (AMODE <= OPM_SPL_COL);
    constexpr bool BSPL = (BMODE <= OPM_SPL_COL);
    // R14: XOR-swizzled LDS layout active for NW8 COL-staged operands
    constexpr bool AX = (AMODE == OPM_B16_COL || AMODE == OPM_WGT_COL) && (NW == 8);
    constexpr bool BX = (BMODE == OPM_B16_COL || BMODE == OPM_WGT_COL) && (NW == 8);
    constexpr int NF = NT / 16;
    constexpr int MI = 8 / NW;         // 16-row frags per wave (2 @NW4, 1 @NW8)
    constexpr int RPW = 128 / NW;      // rows per wave
    __shared__ __align__(16) us Ah[128 * LDSTRIDE];
    __shared__ __align__(16) us Al[ASPL ? 128 * LDSTRIDE : 8];
    __shared__ __align__(16) us Bh[NT * LDSTRIDE];
    __shared__ __align__(16) us Bl[BSPL ? NT * LDSTRIDE : 8];
    __shared__ float redm[(EPI >= 3) ? NW * NT : 1];
    __shared__ float reds[(EPI >= 3) ? NW * NT : 1];

    const int tid = threadIdx.x;
    const int w = tid >> 6, lane = tid & 63;
    const int quad = lane >> 4, l16 = lane & 15;

    // R11b: XCD-chunked bijective swizzle — consecutive work ids share one
    // XCD's L2 (all grids here have nwg % 8 == 0).
    int bx = blockIdx.x, by = blockIdx.y, bz = blockIdx.z;
    {
        const int nbx = gridDim.x, nby = gridDim.y, nbz = gridDim.z;
        const int nwg = nbx * nby * nbz;
        if ((nwg & 7) == 0) {
            const int hw = bx + nbx * (by + nby * bz);
            const int cpx = nwg >> 3;
            int wk = (hw & 7) * cpx + (hw >> 3);
            bx = wk % nbx; wk /= nbx;
            by = wk % nby; bz = wk / nby;
        }
    }

    const int m0 = bx * 128, n0 = by * NT;
    const int b = bz;

    const char* Ab0 = (const char*)A0 + (long long)b * sA;
    const char* Ab1 = A1 ? (const char*)A1 + (long long)b * sA : nullptr;
    const char* Bb0 = (const char*)B0 + (long long)b * sB;
    const char* Bb1 = B1 ? (const char*)B1 + (long long)b * sB : nullptr;

    // R14: weight-normalization constants per covered row(s); FMA form.
    // NW8 new staging: thread covers m = (tid&15)*8 .. +7 -> 8 pairs.
    float nloA[(AMODE == OPM_WGT_COL && NW == 8) ? 8 : 1];
    float invA[(AMODE == OPM_WGT_COL && NW == 8) ? 8 : 1];
    if constexpr (AMODE == OPM_WGT_COL) {
        const float* wloA = wlo + (long long)b * M;
        const float* whiA = whi + (long long)b * M;
        if constexpr (NW == 8) {
            const int mb = m0 + (tid & 15) * 8;
            #pragma unroll
            for (int j = 0; j < 8; ++j) {
                const float lo = wloA[mb + j];
                invA[j] = 1.0f / (whiA[mb + j] - lo + 1e-8f);
                nloA[j] = -lo * invA[j];
            }
        } else {
            const float lo = wloA[m0 + (tid & 127)];
            invA[0] = 1.0f / (whiA[m0 + (tid & 127)] - lo + 1e-8f);
            nloA[0] = -lo * invA[0];
        }
    } else {
        nloA[0] = 0.f; invA[0] = 0.f;
    }

    // R13: TWO named staging slots (rule #20: no runtime-indexed reg arrays).
    SRegs<AMODE, 128, NW> RA0, RA1;
    SRegs<BMODE, NT, NW>  RB0, RB1;
    if constexpr (PREF) {
        stage_load<AMODE, 128, NW>(Ab0, Ab1, lda, m0, 0, tid, RA0);
        stage_load<BMODE, NT, NW>(Bb0, Bb1, ldb, n0, 0, tid, RB0);
        stage_load<AMODE, 128, NW>(Ab0, Ab1, lda, m0, 32, tid, RA1);
        stage_load<BMODE, NT, NW>(Bb0, Bb1, ldb, n0, 32, tid, RB1);
    }

    floatx4 acc[MI][NF];
    #pragma unroll
    for (int mi = 0; mi < MI; ++mi)
        #pragma unroll
        for (int ni = 0; ni < NF; ++ni)
            acc[mi][ni] = (floatx4){0.f, 0.f, 0.f, 0.f};

    auto do_mfma = [&]() {
        short8v ah[MI], al[MI];
        #pragma unroll
        for (int mi = 0; mi < MI; ++mi) {
            const int rowA = RPW * w + 16 * mi + l16;
            const int cA = AX ? (quad ^ ((rowA >> 3) & 3)) : quad;
            const int r = rowA * LDSTRIDE + cA * 8;
            ah[mi] = *(const short8v*)&Ah[r];
            if constexpr (ASPL) al[mi] = *(const short8v*)&Al[r];
        }
        #pragma unroll
        for (int ni = 0; ni < NF; ++ni) {
            const int rowB = 16 * ni + l16;
            const int cB = BX ? (quad ^ ((rowB >> 3) & 3)) : quad;
            const int rB = rowB * LDSTRIDE + cB * 8;
            short8v bh = *(const short8v*)&Bh[rB];
            #pragma unroll
            for (int mi = 0; mi < MI; ++mi)
                acc[mi][ni] = __builtin_amdgcn_mfma_f32_16x16x32_bf16(ah[mi], bh, acc[mi][ni], 0, 0, 0);
            if constexpr (BSPL) {
                short8v bl = *(const short8v*)&Bl[rB];
                #pragma unroll
                for (int mi = 0; mi < MI; ++mi)
                    acc[mi][ni] = __builtin_amdgcn_mfma_f32_16x16x32_bf16(ah[mi], bl, acc[mi][ni], 0, 0, 0);
            }
            if constexpr (ASPL) {
                #pragma unroll
                for (int mi = 0; mi < MI; ++mi)
                    acc[mi][ni] = __builtin_amdgcn_mfma_f32_16x16x32_bf16(al[mi], bh, acc[mi][ni], 0, 0, 0);
            }
        }
    };

    // R13 k-loop: raw barriers (lgkm drained, vmcnt NOT drained) so prefetch
    // loads survive the barrier; 2 named slots, loads issued 2 phases ahead.
#define GEMM_SUBSTEP(RAx, RBx, KCUR, KNEXT)                                    \
    do {                                                                       \
        if constexpr (!PREF) {                                                 \
            stage_load<AMODE, 128, NW>(Ab0, Ab1, lda, m0, (KCUR), tid, RAx);   \
            stage_load<BMODE, NT, NW>(Bb0, Bb1, ldb, n0, (KCUR), tid, RBx);    \
        }                                                                      \
        stage_store<AMODE, 128, NW>(RAx, Ah, Al, tid, nloA, invA);             \
        stage_store<BMODE, NT, NW>(RBx, Bh, Bl, tid, nullptr, nullptr);        \
        if constexpr (PREF) {                                                  \
            asm volatile("s_waitcnt lgkmcnt(0)" ::: "memory");                 \
            __builtin_amdgcn_s_barrier();                                      \
            if ((KNEXT) < K) {                                                 \
                stage_load<AMODE, 128, NW>(Ab0, Ab1, lda, m0, (KNEXT), tid, RAx); \
                stage_load<BMODE, NT, NW>(Bb0, Bb1, ldb, n0, (KNEXT), tid, RBx);  \
            }                                                                  \
        } else {                                                               \
            __syncthreads();                                                   \
        }                                                                      \
        do_mfma();                                                             \
        if constexpr (PREF) {                                                  \
            asm volatile("s_waitcnt lgkmcnt(0)" ::: "memory");                 \
            __builtin_amdgcn_s_barrier();                                      \
        } else {                                                               \
            __syncthreads();                                                   \
        }                                                                      \
    } while (0)

    for (int k0 = 0; k0 < K; k0 += 64) {
        GEMM_SUBSTEP(RA0, RB0, k0, k0 + 64);
        GEMM_SUBSTEP(RA1, RB1, k0 + 32, k0 + 96);
    }
#undef GEMM_SUBSTEP

    if constexpr (EPI != 4) {
        char* Cb0 = (char*)C0 + (long long)b * sC;
        #pragma unroll
        for (int mi = 0; mi < MI; ++mi)
            #pragma unroll
            for (int ni = 0; ni < NF; ++ni)
                #pragma unroll
                for (int r = 0; r < 4; ++r) {
                    const int row = m0 + RPW * w + 16 * mi + quad * 4 + r;
                    const int col = n0 + 16 * ni + l16;
                    float v = acc[mi][ni][r];
                    if constexpr (EPI == 1) v += bias[col];
                    const long long idx = (long long)row * ldc + col;
                    if constexpr (OMODE == OUT_F32) ((float*)Cb0)[idx] = v;
                    else                            ((us*)Cb0)[idx] = f2bf(v);
                }
    }

    if constexpr (EPI == 3) {
        // per-column min/max of bf16-rounded stored values -> 8 partials/(b,s)
        #pragma unroll
        for (int ni = 0; ni < NF; ++ni) {
            float lo = 1e30f, hi = -1e30f;
            #pragma unroll
            for (int mi = 0; mi < MI; ++mi)
                #pragma unroll
                for (int r = 0; r < 4; ++r) {
                    const float vr = bf2f(f2bf(acc[mi][ni][r]));
                    lo = fminf(lo, vr); hi = fmaxf(hi, vr);
                }
            lo = fminf(lo, __shfl_xor(lo, 16)); lo = fminf(lo, __shfl_xor(lo, 32));
            hi = fmaxf(hi, __shfl_xor(hi, 16)); hi = fmaxf(hi, __shfl_xor(hi, 32));
            if (quad == 0) {
                redm[w * NT + 16 * ni + l16] = lo;
                reds[w * NT + 16 * ni + l16] = hi;
            }
        }
        __syncthreads();
        if (tid < NT) {
            float lo = 1e30f, hi = -1e30f;
            #pragma unroll
            for (int w4 = 0; w4 < NW; ++w4) {
                lo = fminf(lo, redm[w4 * NT + tid]);
                hi = fmaxf(hi, reds[w4 * NT + tid]);
            }
            const long long o = ((long long)b * N + n0 + tid) * 8 + bx;
            aux0[o] = lo; aux1[o] = hi;
        }
    }

    if constexpr (EPI == 4) {
        // f_sim never stored: emit row/col LSE partials + diagonal.
        float bn[NF];
        #pragma unroll
        for (int ni = 0; ni < NF; ++ni)
            bn[ni] = invn[(long long)b * N + n0 + 16 * ni + l16] * scale;
        float amv[MI * 4];
        #pragma unroll
        for (int mi = 0; mi < MI; ++mi)
            #pragma unroll
            for (int r = 0; r < 4; ++r)
                amv[mi * 4 + r] = invm[(long long)b * M + m0 + RPW * w + 16 * mi + quad * 4 + r];

        // row pass: lse over this block's NT cols, reduce across l16
        #pragma unroll
        for (int mi = 0; mi < MI; ++mi)
            #pragma unroll
            for (int r = 0; r < 4; ++r) {
                const int grow = m0 + RPW * w + 16 * mi + quad * 4 + r;
                float vv[NF];
                float rm = -1e30f;
                #pragma unroll
                for (int ni = 0; ni < NF; ++ni) {
                    const float v = acc[mi][ni][r] * amv[mi * 4 + r] * bn[ni];
                    vv[ni] = v;
                    rm = fmaxf(rm, v);
                    if (grow == n0 + 16 * ni + l16)
                        aux4[(long long)b * M + grow] = v;
                }
                #pragma unroll
                for (int o = 8; o > 0; o >>= 1) rm = fmaxf(rm, __shfl_xor(rm, o));
                float rs = 0.f;
                #pragma unroll
                for (int ni = 0; ni < NF; ++ni) rs += expf(vv[ni] - rm);
                #pragma unroll
                for (int o = 8; o > 0; o >>= 1) rs += __shfl_xor(rs, o);
                if (l16 == 0) {
                    const long long o = ((long long)b * M + grow) * 4 + by;
                    aux0[o] = rm; aux1[o] = rs;
                }
            }

        // col pass: lse over this block's 128 rows, reduce across quads + waves
        #pragma unroll
        for (int ni = 0; ni < NF; ++ni) {
            float va[MI * 4];
            float cm = -1e30f;
            #pragma unroll
            for (int mi = 0; mi < MI; ++mi)
                #pragma unroll
                for (int r = 0; r < 4; ++r) {
                    const float v = acc[mi][ni][r] * amv[mi * 4 + r] * bn[ni];
                    va[mi * 4 + r] = v;
                    cm = fmaxf(cm, v);
                }
            cm = fmaxf(cm, __shfl_xor(cm, 16));
            cm = fmaxf(cm, __shfl_xor(cm, 32));
            float cs = 0.f;
            #pragma unroll
            for (int j = 0; j < MI * 4; ++j) cs += expf(va[j] - cm);
            cs += __shfl_xor(cs, 16);
            cs += __shfl_xor(cs, 32);
            if (quad == 0) {
                redm[w * NT + 16 * ni + l16] = cm;
                reds[w * NT + 16 * ni + l16] = cs;
            }
        }
        __syncthreads();
        if (tid < NT) {
            float m = -1e30f, s = 0.f;
            #pragma unroll
            for (int w4 = 0; w4 < NW; ++w4) {
                const float cm = redm[w4 * NT + tid], cs = reds[w4 * NT + tid];
                const float nm = fmaxf(m, cm);
                s = s * expf(m - nm) + cs * expf(cm - nm);
                m = nm;
            }
            const long long o = ((long long)b * N + n0 + tid) * 4 + bx;
            aux2[o] = m; aux3[o] = s;
        }
    }
}

// =====================  small kernels  =====================

__global__ __launch_bounds__(256) void convert_w_k(
    const float* Wv, const float* Wt, us* Wvh, us* Wvl, us* Wth, us* Wtl)
{
    const int i = blockIdx.x * 256 + threadIdx.x;
    split_bf(Wv[i], Wvh[i], Wvl[i]);
    split_bf(Wt[i], Wth[i], Wtl[i]);
}

__global__ __launch_bounds__(256) void mean_img_k(
    const float* __restrict__ img, float* __restrict__ mimg)
{
    const int row = blockIdx.x * 4 + (threadIdx.x >> 6);
    const int lane = threadIdx.x & 63;
    const float* p = img + (long long)row * 1024;
    float s = 0.f;
    #pragma unroll
    for (int c = 0; c < 4; ++c) {
        float4 v = *(const float4*)&p[(c * 64 + lane) * 4];
        s += v.x + v.y + v.z + v.w;
    }
    #pragma unroll
    for (int o = 32; o > 0; o >>= 1) s += __shfl_xor(s, o);
    if (lane == 0) mimg[row] = s * (1.0f / 1024.0f);
}

__global__ __launch_bounds__(256) void mean_text_s1(
    const float* __restrict__ text, float* __restrict__ part)
{
    const int b = blockIdx.x, ch = blockIdx.y, k = threadIdx.x;
    const float* p = text + ((long long)b * 512 + ch * 64) * 256 + k;
    float s = 0.f;
    for (int r = 0; r < 64; ++r) s += p[r * 256];
    part[(b * 8 + ch) * 256 + k] = s;
}
__global__ __launch_bounds__(256) void mean_text_s2(
    const float* __restrict__ part, float* __restrict__ mt)
{
    const int b = blockIdx.x, k = threadIdx.x;
    float s = 0.f;
    for (int c = 0; c < 8; ++c) s += part[(b * 8 + c) * 256 + k];
    mt[b * 256 + k] = s * (1.0f / 512.0f);
}

__global__ __launch_bounds__(256) void small_adapter_k(
    const float* __restrict__ x, const float* __restrict__ W,
    const float* __restrict__ bias, float* __restrict__ y)
{
    const int b = blockIdx.x, d = threadIdx.x;
    __shared__ float xs[256];
    xs[d] = x[b * 256 + d];
    __syncthreads();
    const float4* w = (const float4*)(W + (long long)d * 256);
    const float4* xv = (const float4*)xs;
    float s = bias[d];
    #pragma unroll 8
    for (int k = 0; k < 64; ++k) {
        const float4 a = xv[k], ww = w[k];
        s += a.x * ww.x + a.y * ww.y + a.z * ww.z + a.w * ww.w;
    }
    y[b * 256 + d] = s;
}

// ---- parallelized global loss ----

__global__ __launch_bounds__(256) void inv_norm_f32_k(
    const float* __restrict__ x, float* __restrict__ inv)
{
    const int row = blockIdx.x * 4 + (threadIdx.x >> 6);
    const int lane = threadIdx.x & 63;
    float4 v = *(const float4*)&x[(long long)row * 256 + lane * 4];
    float s = v.x * v.x + v.y * v.y + v.z * v.z + v.w * v.w;
    #pragma unroll
    for (int o = 32; o > 0; o >>= 1) s += __shfl_xor(s, o);
    if (lane == 0) inv[row] = 1.0f / fmaxf(sqrtf(s), 1e-8f);
}

__global__ __launch_bounds__(256) void g_sim_k(
    const float* __restrict__ gi, const float* __restrict__ gt,
    const float* __restrict__ invI, const float* __restrict__ invT,
    float* __restrict__ gs)
{
    const int i = blockIdx.x, t = threadIdx.x;
    const int j = t >> 2, part = t & 3;
    __shared__ float a[256];
    a[t] = gi[i * 256 + t];
    __syncthreads();
    const float* bp = gt + (long long)j * 256 + part * 64;
    const float* ap = a + part * 64;
    float s = 0.f;
    #pragma unroll 16
    for (int k = 0; k < 64; ++k) s += ap[k] * bp[k];
    s += __shfl_xor(s, 1);
    s += __shfl_xor(s, 2);
    if (part == 0) gs[i * 64 + j] = s * invI[i] * invT[j] * TAU_INV;
}

__global__ __launch_bounds__(64) void g_lse_k(
    const float* __restrict__ gs, float* __restrict__ out)
{
    const int b = blockIdx.x, lane = threadIdx.x;
    const bool is_col = b >= 64;
    const int r = is_col ? b - 64 : b;
    const float v = is_col ? gs[lane * 64 + r] : gs[r * 64 + lane];
    float m = v;
    #pragma unroll
    for (int o = 32; o > 0; o >>= 1) m = fmaxf(m, __shfl_xor(m, o));
    float s = expf(v - m);
    #pragma unroll
    for (int o = 32; o > 0; o >>= 1) s += __shfl_xor(s, o);
    if (lane == 0)
        atomicAdd(out, ((m + logf(s)) - gs[r * 64 + r]) * (0.5f / 64.0f));
}

// inv L2 norm of 256-wide single-bf16 rows
__global__ __launch_bounds__(256) void inv_norm_b16_k(
    const us* __restrict__ x, float* __restrict__ inv)
{
    const int row = blockIdx.x * 4 + (threadIdx.x >> 6);
    const int lane = threadIdx.x & 63;
    ushort4 h = *(const ushort4*)&x[(long long)row * 256 + lane * 4];
    const float x0 = bf2f(h.x), x1 = bf2f(h.y), x2 = bf2f(h.z), x3 = bf2f(h.w);
    float s = x0 * x0 + x1 * x1 + x2 * x2 + x3 * x3;
    #pragma unroll
    for (int o = 32; o > 0; o >>= 1) s += __shfl_xor(s, o);
    if (lane == 0) inv[row] = 1.0f / fmaxf(sqrtf(s), 1e-8f);
}

// ---- merge kernels ----

// merge 8 minmax partials per (b,s); grid 128 x 256
__global__ __launch_bounds__(256) void minmax_merge_k(
    const float* __restrict__ mnp, const float* __restrict__ mxp,
    float* __restrict__ mn, float* __restrict__ mx)
{
    const int idx = blockIdx.x * 256 + threadIdx.x;
    float lo = 1e30f, hi = -1e30f;
    #pragma unroll
    for (int c = 0; c < 8; ++c) {
        lo = fminf(lo, mnp[(long long)idx * 8 + c]);
        hi = fmaxf(hi, mxp[(long long)idx * 8 + c]);
    }
    mn[idx] = lo; mx[idx] = hi;
}

// merge 4 LSE partials per row/col, subtract diag; grid 128 x 256
__global__ __launch_bounds__(256) void fine_merge4_k(
    const float* __restrict__ pm, const float* __restrict__ ps,
    const float* __restrict__ diag, float* __restrict__ out)
{
    const int idx = blockIdx.x * 256 + threadIdx.x;
    float m = -1e30f, s = 0.f;
    #pragma unroll
    for (int c = 0; c < 4; ++c) {
        const float cm = pm[(long long)idx * 4 + c], cs = ps[(long long)idx * 4 + c];
        const float nm = fmaxf(m, cm);
        s = s * expf(m - nm) + cs * expf(cm - nm);
        m = nm;
    }
    const float contrib = (m + logf(s)) - diag[idx];
    __shared__ float red[256];
    red[threadIdx.x] = contrib;
    __syncthreads();
    for (int w = 128; w > 0; w >>= 1) {
        if (threadIdx.x < w) red[threadIdx.x] += red[threadIdx.x + w];
        __syncthreads();
    }
    if (threadIdx.x == 0) atomicAdd(out, red[0] * (0.5f / (64.0f * 512.0f)));
}

extern "C" void kernel_launch(void* const* d_in, const int* in_sizes, int n_in,
                              void* d_out, int out_size, void* d_ws, size_t ws_size,
                              hipStream_t stream)
{
    const float* img  = (const float*)d_in[0];
    const float* text = (const float*)d_in[1];
    const float* Wv   = (const float*)d_in[2];
    const float* bv   = (const float*)d_in[3];
    const float* Wt   = (const float*)d_in[4];
    const float* bt   = (const float*)d_in[5];
    float* out = (float*)d_out;
    char* ws = (char*)d_ws;

    us* patches = (us*)(ws + 0);              // 33,554,432 B
    us* tokens  = (us*)(ws + 33554432);       // 16,777,216 B
    us* simW    = (us*)(ws + 50331648);       // 67,108,864 B
    us* lgve    = (us*)(ws + 117440512);      // 16,777,216 B
    char* st = ws + 134217728;
    float* mean_img  = (float*)(st + 0);
    float* mean_text = (float*)(st + 65536);
    float* mean_pat  = (float*)(st + 131072);
    float* mean_tok  = (float*)(st + 196608);
    float* g_img     = (float*)(st + 262144);
    float* g_txt     = (float*)(st + 327680);
    float* textpart  = (float*)(st + 393216);
    float* mnp       = (float*)(st + 917504);   // 1 MB
    float* mxp       = (float*)(st + 1966080);  // 1 MB
    float* mnv       = (float*)(st + 3014656);
    float* mxv       = (float*)(st + 3145728);
    float* inv_l     = (float*)(st + 3276800);
    float* inv_t     = (float*)(st + 3407872);
    us* Wvh = (us*)(st + 3538944);
    us* Wvl = (us*)(st + 3670016);
    us* Wth = (us*)(st + 3801088);
    us* Wtl = (us*)(st + 3932160);
    float* inv_gi  = (float*)(st + 4063232);
    float* inv_gt  = (float*)(st + 4063744);
    float* g_simbf = (float*)(st + 4064256);
    float* pm_row  = (float*)(st + 4194304);   // 512 KB (4 partials/row)
    float* ps_row  = (float*)(st + 4718592);   // 512 KB
    float* pm_col  = (float*)(st + 5242880);   // 512 KB
    float* ps_col  = (float*)(st + 5767168);   // 512 KB
    float* diag    = (float*)(st + 6291456);   // 128 KB

    zero_out_k<<<1, 64, 0, stream>>>(out);
    convert_w_k<<<256, 256, 0, stream>>>(Wv, Wt, Wvh, Wvl, Wth, Wtl);

    // Global path (mean commutes with linear)
    mean_img_k<<<4096, 256, 0, stream>>>(img, mean_img);
    mean_text_s1<<<dim3(64, 8), 256, 0, stream>>>(text, textpart);
    mean_text_s2<<<64, 256, 0, stream>>>(textpart, mean_text);
    small_adapter_k<<<BB, 256, 0, stream>>>(mean_img, Wv, bv, mean_pat);
    small_adapter_k<<<BB, 256, 0, stream>>>(mean_pat, Wv, bv, g_img);
    small_adapter_k<<<BB, 256, 0, stream>>>(mean_text, Wt, bt, mean_tok);
    small_adapter_k<<<BB, 256, 0, stream>>>(mean_tok, Wt, bt, g_txt);
    inv_norm_f32_k<<<16, 256, 0, stream>>>(g_img, inv_gi);
    inv_norm_f32_k<<<16, 256, 0, stream>>>(g_txt, inv_gt);
    g_sim_k<<<64, 256, 0, stream>>>(g_img, g_txt, inv_gi, inv_gt, g_simbf);
    g_lse_k<<<128, 64, 0, stream>>>(g_simbf, out);

    // G1: patches = img.Wv + bv (split internally, bf16 out; NT=256 -> img x1)
    mfma_gemm<OPM_F32_COL, OPM_SPL_ROW, OUT_B16, 1, 256, 0, 4><<<dim3(8, 1, BB), 256, 0, stream>>>(
        img, nullptr, Wvh, Wvl, patches,
        1024, 256, 256, 1024, 256, 256,
        1048576LL, 0LL, 524288LL, bv, nullptr, nullptr, 0.f, nullptr, nullptr,
        nullptr, nullptr, nullptr, nullptr, nullptr);

    // G2: tokens = text.Wt + bt
    mfma_gemm<OPM_F32_ROW, OPM_SPL_ROW, OUT_B16, 1, 256, 0, 4><<<dim3(4, 1, BB), 256, 0, stream>>>(
        text, nullptr, Wth, Wtl, tokens,
        512, 256, 256, 256, 256, 256,
        524288LL, 0LL, 262144LL, bt, nullptr, nullptr, 0.f, nullptr, nullptr,
        nullptr, nullptr, nullptr, nullptr, nullptr);

    // G4: sim = patches.tokens^T, minmax fused; NT=128, 2-deep pipeline
    mfma_gemm<OPM_B16_ROW, OPM_B16_ROW, OUT_B16, 3, 128, 1, 4><<<dim3(8, 4, BB), 256, 0, stream>>>(
        patches, nullptr, tokens, nullptr, simW,
        1024, 512, 256, 256, 256, 512,
        524288LL, 262144LL, 1048576LL, nullptr, nullptr, nullptr, 0.f, nullptr, nullptr,
        mnp, mxp, nullptr, nullptr, nullptr);

    minmax_merge_k<<<128, 256, 0, stream>>>(mnp, mxp, mnv, mxv);

    // G6: lgve = w.patches; NW=8, 2-deep pipeline, R14 wide COL staging
    mfma_gemm<OPM_WGT_COL, OPM_B16_COL, OUT_B16, 0, 128, 1, 8><<<dim3(4, 2, BB), 512, 0, stream>>>(
        simW, nullptr, patches, nullptr, lgve,
        512, 256, 1024, 512, 256, 256,
        1048576LL, 524288LL, 262144LL, nullptr, nullptr, nullptr, 0.f, mnv, mxv,
        nullptr, nullptr, nullptr, nullptr, nullptr);

    inv_norm_b16_k<<<8192, 256, 0, stream>>>(lgve, inv_l);
    inv_norm_b16_k<<<8192, 256, 0, stream>>>(tokens, inv_t);

    // G8: f_sim never materialized; NW=8, 2-deep pipeline
    mfma_gemm<OPM_B16_ROW, OPM_B16_ROW, OUT_B16, 4, 128, 1, 8><<<dim3(4, 4, BB), 512, 0, stream>>>(
        lgve, nullptr, tokens, nullptr, nullptr,
        512, 512, 256, 256, 256, 512,
        262144LL, 262144LL, 0LL, nullptr, inv_l, inv_t, TAU_INV, nullptr, nullptr,
        pm_row, ps_row, pm_col, ps_col, diag);

    fine_merge4_k<<<128, 256, 0, stream>>>(pm_row, ps_row, diag, out);
    fine_merge4_k<<<128, 256, 0, stream>>>(pm_col, ps_col, diag, out);
}

// Round 5
// 395.504 us; speedup vs baseline: 1.0009x; 1.0009x over previous
//
#include <hip/hip_runtime.h>
#include <math.h>

#define BB   64
#define HWP  1024
#define SS   512
#define DD   256
#define TAU_INV (1.0f/0.07f)
#define SIGMA   (1.0f/1024.0f)

typedef unsigned short us;
typedef __attribute__((ext_vector_type(8))) short short8v;
typedef __attribute__((ext_vector_type(8))) unsigned short ushort8v;
typedef __attribute__((ext_vector_type(4))) float floatx4;

__device__ __forceinline__ float bf2f(us u) {
    return __uint_as_float((unsigned)u << 16);
}
__device__ __forceinline__ us f2bf(float f) {
    unsigned u = __float_as_uint(f);
    u += 0x7FFFu + ((u >> 16) & 1u);
    return (us)(u >> 16);
}
__device__ __forceinline__ void split_bf(float v, us& h, us& l) {
    h = f2bf(v);
    l = f2bf(v - bf2f(h));
}

// R15: HBM->LDS DMA, bypasses VGPRs entirely (regalloc cannot sink it).
__device__ __forceinline__ void dma16(const us* g, us* l) {
    __builtin_amdgcn_global_load_lds(
        (const __attribute__((address_space(1))) unsigned int*)g,
        (__attribute__((address_space(3))) unsigned int*)l, 16, 0, 0);
}

__global__ void zero_out_k(float* out) { if (threadIdx.x == 0) out[0] = 0.0f; }

// =====================  MFMA GEMM  =====================
// C[m,n] = sum_k A(m,k)*B(n,k). Tile 128 x NT, BK=32, 16x16x32 bf16 MFMA.
// R11-R14 post-mortem: all register-staged prefetch schemes were defeated by
// regalloc (VGPR_Count=48 -> loads sunk to use site -> ~2x mem latency exposed
// per substep, 2160cy/substep measured vs ~350 ideal). R14's b16 LDS scatter
// swizzle hit the wrong axis (row-block stride 320 elems = 0 mod 32 banks).
// R15: (a) G4'/G8 staged via global_load_lds into double-buffered LINEAR LDS
//          (stride 32) with counted vmcnt(2) + raw barriers — the m97 pattern.
//      (b) G4 -> G4': simT = tokens . patches^T (swapped operands; bitwise
//          identical values), row-minmax epilogue (wave-local, no LDS).
//      (c) G6: A = simT row-wise (WGT_ROW: 1 wide load + uniform per-row
//          weight constants); B reverts to R13 scalar COL staging.
enum { OPM_F32_ROW = 0, OPM_F32_COL = 1, OPM_SPL_ROW = 2, OPM_SPL_COL = 3,
       OPM_B16_COL = 4, OPM_B16_ROW = 5, OPM_WGT_COL = 6, OPM_WGT_ROW = 7 };
enum { OUT_F32 = 0, OUT_B16 = 1 };

#define LDSTRIDE 40

template<int MODE, int ROWS, int NW>
struct SRegs {
    static constexpr int RR = ROWS / 128;
    static constexpr bool ISF32 = (MODE == OPM_F32_ROW) || (MODE == OPM_F32_COL);
    ushort8v h[ISF32 ? 1 : RR][2];     // NW==8 paths use [rr][0] only (DCE'd)
    ushort8v l[(MODE == OPM_SPL_ROW) ? RR : 1][2];
    float4   f[ISF32 ? RR : 1][4];
};

// global -> registers (raw data, no conversion math)
template<int MODE, int ROWS, int NW>
__device__ __forceinline__ void stage_load(
    const char* p0, const char* p1, int ld, int row0, int k0, int tid,
    SRegs<MODE, ROWS, NW>& R)
{
    #pragma unroll
    for (int rr = 0; rr < ROWS / 128; ++rr) {
        if constexpr (MODE == OPM_SPL_ROW) {
            // NW==4 only
            const us* ph = (const us*)p0;
            const us* pl = (const us*)p1;
            const int i = rr * 128 + (tid >> 1), ko = (tid & 1) * 16;
            const long long g = (long long)(row0 + i) * ld + k0 + ko;
            R.h[rr][0] = *(const ushort8v*)&ph[g];
            R.h[rr][1] = *(const ushort8v*)&ph[g + 8];
            R.l[rr][0] = *(const ushort8v*)&pl[g];
            R.l[rr][1] = *(const ushort8v*)&pl[g + 8];
        } else if constexpr (MODE == OPM_B16_ROW || MODE == OPM_WGT_ROW) {
            const us* ph = (const us*)p0;
            if constexpr (NW == 4) {
                const int i = rr * 128 + (tid >> 1), ko = (tid & 1) * 16;
                const long long g = (long long)(row0 + i) * ld + k0 + ko;
                R.h[rr][0] = *(const ushort8v*)&ph[g];
                R.h[rr][1] = *(const ushort8v*)&ph[g + 8];
            } else {
                const int i = rr * 128 + (tid >> 2), ko = (tid & 3) * 8;
                const long long g = (long long)(row0 + i) * ld + k0 + ko;
                R.h[rr][0] = *(const ushort8v*)&ph[g];
            }
        } else if constexpr (MODE == OPM_F32_ROW) {
            // NW==4 only
            const float* pf = (const float*)p0;
            const int i = rr * 128 + (tid >> 1), ko = (tid & 1) * 16;
            const long long g = (long long)(row0 + i) * ld + k0 + ko;
            #pragma unroll
            for (int c = 0; c < 4; ++c)
                R.f[rr][c] = *(const float4*)&pf[g + c * 4];
        } else if constexpr (MODE == OPM_F32_COL) {
            // NW==4 only (G1)
            const float* pf = (const float*)p0;
            const int m = rr * 128 + (tid & 127), kh = (tid >> 7) * 16;
            const long long base = (long long)(k0 + kh) * ld + row0 + m;
            #pragma unroll
            for (int c = 0; c < 4; ++c) {
                float4 v;
                v.x = pf[base + (long long)(c * 4 + 0) * ld];
                v.y = pf[base + (long long)(c * 4 + 1) * ld];
                v.z = pf[base + (long long)(c * 4 + 2) * ld];
                v.w = pf[base + (long long)(c * 4 + 3) * ld];
                R.f[rr][c] = v;
            }
        } else if constexpr (MODE == OPM_B16_COL) {
            const us* ph = (const us*)p0;
            if constexpr (NW == 4) {
                const int m = rr * 128 + (tid & 127), kh = (tid >> 7) * 16;
                const long long base = (long long)(k0 + kh) * ld + row0 + m;
                #pragma unroll
                for (int kk = 0; kk < 8; ++kk) {
                    R.h[rr][0][kk] = ph[base + (long long)kk * ld];
                    R.h[rr][1][kk] = ph[base + (long long)(kk + 8) * ld];
                }
            } else {
                const int m = rr * 128 + (tid & 127), kh = (tid >> 7) * 8;
                const long long base = (long long)(k0 + kh) * ld + row0 + m;
                #pragma unroll
                for (int kk = 0; kk < 8; ++kk)
                    R.h[rr][0][kk] = ph[base + (long long)kk * ld];
            }
        }
    }
}

// registers -> LDS (conversion / weight math happens here)
template<int MODE, int ROWS, int NW>
__device__ __forceinline__ void stage_store(
    const SRegs<MODE, ROWS, NW>& R, us* ldsH, us* ldsL, int tid, float nlo, float inv)
{
    #pragma unroll
    for (int rr = 0; rr < ROWS / 128; ++rr) {
        if constexpr (MODE == OPM_SPL_ROW) {
            const int i = rr * 128 + (tid >> 1), ko = (tid & 1) * 16;
            *(ushort8v*)&ldsH[i * LDSTRIDE + ko]     = R.h[rr][0];
            *(ushort8v*)&ldsH[i * LDSTRIDE + ko + 8] = R.h[rr][1];
            *(ushort8v*)&ldsL[i * LDSTRIDE + ko]     = R.l[rr][0];
            *(ushort8v*)&ldsL[i * LDSTRIDE + ko + 8] = R.l[rr][1];
        } else if constexpr (MODE == OPM_B16_ROW) {
            if constexpr (NW == 4) {
                const int i = rr * 128 + (tid >> 1), ko = (tid & 1) * 16;
                *(ushort8v*)&ldsH[i * LDSTRIDE + ko]     = R.h[rr][0];
                *(ushort8v*)&ldsH[i * LDSTRIDE + ko + 8] = R.h[rr][1];
            } else {
                const int i = rr * 128 + (tid >> 2), ko = (tid & 3) * 8;
                *(ushort8v*)&ldsH[i * LDSTRIDE + ko] = R.h[rr][0];
            }
        } else if constexpr (MODE == OPM_WGT_ROW) {
            // R15c: row-staged simT + uniform per-row weight transform (NW8)
            const int i = tid >> 2, ko = (tid & 3) * 8;
            us v[8];
            #pragma unroll
            for (int j = 0; j < 8; ++j) {
                const float w0 = fmaf(bf2f(R.h[0][0][j]), inv, nlo);
                v[j] = (w0 < SIGMA) ? (us)0 : f2bf(w0);
            }
            *(ushort8v*)&ldsH[i * LDSTRIDE + ko] = *(const ushort8v*)&v[0];
        } else if constexpr (MODE == OPM_F32_ROW) {
            const int i = rr * 128 + (tid >> 1), ko = (tid & 1) * 16;
            us h16[16], l16a[16];
            #pragma unroll
            for (int c = 0; c < 4; ++c) {
                float4 v = R.f[rr][c];
                split_bf(v.x, h16[c*4+0], l16a[c*4+0]);
                split_bf(v.y, h16[c*4+1], l16a[c*4+1]);
                split_bf(v.z, h16[c*4+2], l16a[c*4+2]);
                split_bf(v.w, h16[c*4+3], l16a[c*4+3]);
            }
            *(ushort8v*)&ldsH[i * LDSTRIDE + ko]     = *(const ushort8v*)&h16[0];
            *(ushort8v*)&ldsH[i * LDSTRIDE + ko + 8] = *(const ushort8v*)&h16[8];
            *(ushort8v*)&ldsL[i * LDSTRIDE + ko]     = *(const ushort8v*)&l16a[0];
            *(ushort8v*)&ldsL[i * LDSTRIDE + ko + 8] = *(const ushort8v*)&l16a[8];
        } else if constexpr (MODE == OPM_F32_COL) {
            const int m = rr * 128 + (tid & 127), kh = (tid >> 7) * 16;
            us vh[16], vl[16];
            #pragma unroll
            for (int c = 0; c < 4; ++c) {
                float4 v = R.f[rr][c];
                split_bf(v.x, vh[c*4+0], vl[c*4+0]);
                split_bf(v.y, vh[c*4+1], vl[c*4+1]);
                split_bf(v.z, vh[c*4+2], vl[c*4+2]);
                split_bf(v.w, vh[c*4+3], vl[c*4+3]);
            }
            *(ushort8v*)&ldsH[m * LDSTRIDE + kh]     = *(const ushort8v*)&vh[0];
            *(ushort8v*)&ldsH[m * LDSTRIDE + kh + 8] = *(const ushort8v*)&vh[8];
            *(ushort8v*)&ldsL[m * LDSTRIDE + kh]     = *(const ushort8v*)&vl[0];
            *(ushort8v*)&ldsL[m * LDSTRIDE + kh + 8] = *(const ushort8v*)&vl[8];
        } else if constexpr (MODE == OPM_B16_COL) {
            if constexpr (NW == 4) {
                const int m = rr * 128 + (tid & 127), kh = (tid >> 7) * 16;
                us v[16];
                #pragma unroll
                for (int kk = 0; kk < 16; ++kk)
                    v[kk] = (kk < 8) ? R.h[rr][0][kk & 7] : R.h[rr][1][kk & 7];
                *(ushort8v*)&ldsH[m * LDSTRIDE + kh]     = *(const ushort8v*)&v[0];
                *(ushort8v*)&ldsH[m * LDSTRIDE + kh + 8] = *(const ushort8v*)&v[8];
            } else {
                const int m = rr * 128 + (tid & 127), kh = (tid >> 7) * 8;
                *(ushort8v*)&ldsH[m * LDSTRIDE + kh] = R.h[rr][0];
            }
        }
    }
}

template<int AMODE, int BMODE, int OMODE, int EPI, int NT, int PREF, int NW, int DMA>
__global__ __launch_bounds__(NW * 64) void mfma_gemm(
    const void* A0, const void* A1, const void* B0, const void* B1, void* C0,
    int M, int N, int K, int lda, int ldb, int ldc,
    long long sA, long long sB, long long sC,
    const float* __restrict__ bias, const float* __restrict__ invm,
    const float* __restrict__ invn, float scale,
    const float* __restrict__ wlo, const float* __restrict__ whi,
    float* __restrict__ aux0, float* __restrict__ aux1,
    float* __restrict__ aux2, float* __restrict__ aux3, float* __restrict__ aux4)
{
    constexpr bool ASPL = (AMODE <= OPM_SPL_COL);
    constexpr bool BSPL = (BMODE <= OPM_SPL_COL);
    constexpr int NF = NT / 16;
    constexpr int MI = 8 / NW;         // 16-row frags per wave (2 @NW4, 1 @NW8)
    constexpr int RPW = 128 / NW;      // rows per wave
    __shared__ __align__(16) us Ah[DMA ? 8 : 128 * LDSTRIDE];
    __shared__ __align__(16) us Al[(!DMA && ASPL) ? 128 * LDSTRIDE : 8];
    __shared__ __align__(16) us Bh[DMA ? 8 : NT * LDSTRIDE];
    __shared__ __align__(16) us Bl[(!DMA && BSPL) ? NT * LDSTRIDE : 8];
    __shared__ __align__(16) us AhD[DMA ? 2 * 128 * 32 : 8];   // linear, dbuf
    __shared__ __align__(16) us BhD[DMA ? 2 * NT * 32 : 8];
    __shared__ float redm[(EPI == 4) ? NW * NT : 1];
    __shared__ float reds[(EPI == 4) ? NW * NT : 1];

    const int tid = threadIdx.x;
    const int w = tid >> 6, lane = tid & 63;
    const int quad = lane >> 4, l16 = lane & 15;

    // XCD-chunked bijective swizzle (nwg % 8 == 0 for all grids here).
    int bx = blockIdx.x, by = blockIdx.y, bz = blockIdx.z;
    {
        const int nbx = gridDim.x, nby = gridDim.y, nbz = gridDim.z;
        const int nwg = nbx * nby * nbz;
        if ((nwg & 7) == 0) {
            const int hw = bx + nbx * (by + nby * bz);
            const int cpx = nwg >> 3;
            int wk = (hw & 7) * cpx + (hw >> 3);
            bx = wk % nbx; wk /= nbx;
            by = wk % nby; bz = wk / nby;
        }
    }

    const int m0 = bx * 128, n0 = by * NT;
    const int b = bz;

    const char* Ab0 = (const char*)A0 + (long long)b * sA;
    const char* Ab1 = A1 ? (const char*)A1 + (long long)b * sA : nullptr;
    const char* Bb0 = (const char*)B0 + (long long)b * sB;
    const char* Bb1 = B1 ? (const char*)B1 + (long long)b * sB : nullptr;

    floatx4 acc[MI][NF];
    #pragma unroll
    for (int mi = 0; mi < MI; ++mi)
        #pragma unroll
        for (int ni = 0; ni < NF; ++ni)
            acc[mi][ni] = (floatx4){0.f, 0.f, 0.f, 0.f};

    if constexpr (DMA) {
        // ================= R15a: DMA-staged pipeline (ROW/ROW only) =========
        // wave w covers 1KB of each 8KB tile: lane l -> row 16w+(l>>2),
        // col-octet l&3; dest offset = 512w + 8*l elems (lane-linear) so the
        // HW rule "uniform base + lane*16B" lands each 16B exactly at
        // [row*32 + col8] of the linear [rows][32] tile.
        const us* Abu = (const us*)Ab0;
        const us* Bbu = (const us*)Bb0;
        const int drow = 16 * w + (lane >> 2);
        const int dcol = (lane & 3) * 8;
        const us* aS = Abu + (long long)(m0 + drow) * lda + dcol;
        const us* bS = Bbu + (long long)(n0 + drow) * ldb + dcol;
        us* aD = &AhD[0] + 512 * w;
        us* bD = &BhD[0] + 512 * w;
        const int NTL = K >> 5;

        dma16(aS,      aD);
        dma16(bS,      bD);
        dma16(aS + 32, aD + 128 * 32);
        dma16(bS + 32, bD + NT * 32);

        int cur = 0;
        for (int t = 0; t < NTL; ++t) {
            if (t + 1 == NTL) asm volatile("s_waitcnt vmcnt(0)" ::: "memory");
            else              asm volatile("s_waitcnt vmcnt(2)" ::: "memory");
            __builtin_amdgcn_s_barrier();
            asm volatile("" ::: "memory");

            {
                const us* Ac = &AhD[cur * 128 * 32];
                const us* Bc = &BhD[cur * NT * 32];
                short8v ah = *(const short8v*)&Ac[(16 * w + l16) * 32 + quad * 8];
                #pragma unroll
                for (int ni = 0; ni < NF; ++ni) {
                    short8v bh = *(const short8v*)&Bc[(16 * ni + l16) * 32 + quad * 8];
                    acc[0][ni] = __builtin_amdgcn_mfma_f32_16x16x32_bf16(ah, bh, acc[0][ni], 0, 0, 0);
                }
            }

            asm volatile("" ::: "memory");
            __builtin_amdgcn_s_barrier();
            if (t + 2 < NTL) {
                const long long off = (long long)(t + 2) * 32;
                dma16(aS + off, aD + cur * 128 * 32);
                dma16(bS + off, bD + cur * NT * 32);
            }
            cur ^= 1;
        }
    } else {
        // ================= reg-staged path (G1/G2/G6) ======================
        float nloA = 0.f, invA = 0.f;
        if constexpr (AMODE == OPM_WGT_ROW) {
            const float* wloA = wlo + (long long)b * M;
            const float* whiA = whi + (long long)b * M;
            const int row = m0 + (tid >> 2);       // NW8 staging row
            const float lo = wloA[row];
            invA = 1.0f / (whiA[row] - lo + 1e-8f);
            nloA = -lo * invA;
        }

        SRegs<AMODE, 128, NW> RA0, RA1;
        SRegs<BMODE, NT, NW>  RB0, RB1;
        if constexpr (PREF) {
            stage_load<AMODE, 128, NW>(Ab0, Ab1, lda, m0, 0, tid, RA0);
            stage_load<BMODE, NT, NW>(Bb0, Bb1, ldb, n0, 0, tid, RB0);
            stage_load<AMODE, 128, NW>(Ab0, Ab1, lda, m0, 32, tid, RA1);
            stage_load<BMODE, NT, NW>(Bb0, Bb1, ldb, n0, 32, tid, RB1);
        }

        auto do_mfma = [&]() {
            short8v ah[MI], al[MI];
            #pragma unroll
            for (int mi = 0; mi < MI; ++mi) {
                const int r = (RPW * w + 16 * mi + l16) * LDSTRIDE + quad * 8;
                ah[mi] = *(const short8v*)&Ah[r];
                if constexpr (ASPL) al[mi] = *(const short8v*)&Al[r];
            }
            #pragma unroll
            for (int ni = 0; ni < NF; ++ni) {
                const int rB = (16 * ni + l16) * LDSTRIDE + quad * 8;
                short8v bh = *(const short8v*)&Bh[rB];
                #pragma unroll
                for (int mi = 0; mi < MI; ++mi)
                    acc[mi][ni] = __builtin_amdgcn_mfma_f32_16x16x32_bf16(ah[mi], bh, acc[mi][ni], 0, 0, 0);
                if constexpr (BSPL) {
                    short8v bl = *(const short8v*)&Bl[rB];
                    #pragma unroll
                    for (int mi = 0; mi < MI; ++mi)
                        acc[mi][ni] = __builtin_amdgcn_mfma_f32_16x16x32_bf16(ah[mi], bl, acc[mi][ni], 0, 0, 0);
                }
                if constexpr (ASPL) {
                    #pragma unroll
                    for (int mi = 0; mi < MI; ++mi)
                        acc[mi][ni] = __builtin_amdgcn_mfma_f32_16x16x32_bf16(al[mi], bh, acc[mi][ni], 0, 0, 0);
                }
            }
        };

#define GEMM_SUBSTEP(RAx, RBx, KCUR, KNEXT)                                    \
    do {                                                                       \
        if constexpr (!PREF) {                                                 \
            stage_load<AMODE, 128, NW>(Ab0, Ab1, lda, m0, (KCUR), tid, RAx);   \
            stage_load<BMODE, NT, NW>(Bb0, Bb1, ldb, n0, (KCUR), tid, RBx);    \
        }                                                                      \
        stage_store<AMODE, 128, NW>(RAx, Ah, Al, tid, nloA, invA);             \
        stage_store<BMODE, NT, NW>(RBx, Bh, Bl, tid, 0.f, 0.f);                \
        if constexpr (PREF) {                                                  \
            asm volatile("s_waitcnt lgkmcnt(0)" ::: "memory");                 \
            __builtin_amdgcn_s_barrier();                                      \
            if ((KNEXT) < K) {                                                 \
                stage_load<AMODE, 128, NW>(Ab0, Ab1, lda, m0, (KNEXT), tid, RAx); \
                stage_load<BMODE, NT, NW>(Bb0, Bb1, ldb, n0, (KNEXT), tid, RBx);  \
            }                                                                  \
        } else {                                                               \
            __syncthreads();                                                   \
        }                                                                      \
        do_mfma();                                                             \
        if constexpr (PREF) {                                                  \
            asm volatile("s_waitcnt lgkmcnt(0)" ::: "memory");                 \
            __builtin_amdgcn_s_barrier();                                      \
        } else {                                                               \
            __syncthreads();                                                   \
        }                                                                      \
    } while (0)

        for (int k0 = 0; k0 < K; k0 += 64) {
            GEMM_SUBSTEP(RA0, RB0, k0, k0 + 64);
            GEMM_SUBSTEP(RA1, RB1, k0 + 32, k0 + 96);
        }
#undef GEMM_SUBSTEP
    }

    if constexpr (EPI != 4) {
        char* Cb0 = (char*)C0 + (long long)b * sC;
        #pragma unroll
        for (int mi = 0; mi < MI; ++mi)
            #pragma unroll
            for (int ni = 0; ni < NF; ++ni)
                #pragma unroll
                for (int r = 0; r < 4; ++r) {
                    const int row = m0 + RPW * w + 16 * mi + quad * 4 + r;
                    const int col = n0 + 16 * ni + l16;
                    float v = acc[mi][ni][r];
                    if constexpr (EPI == 1) v += bias[col];
                    const long long idx = (long long)row * ldc + col;
                    if constexpr (OMODE == OUT_F32) ((float*)Cb0)[idx] = v;
                    else                            ((us*)Cb0)[idx] = f2bf(v);
                }
    }

    if constexpr (EPI == 3) {
        // R15b: ROW min/max of bf16-rounded stored values (C is simT[s][p]).
        // Each row is wave-local: reduce over ni then across l16.
        #pragma unroll
        for (int r = 0; r < 4; ++r) {
            const int grow = m0 + RPW * w + quad * 4 + r;
            float lo = 1e30f, hi = -1e30f;
            #pragma unroll
            for (int ni = 0; ni < NF; ++ni) {
                const float vr = bf2f(f2bf(acc[0][ni][r]));
                lo = fminf(lo, vr); hi = fmaxf(hi, vr);
            }
            lo = fminf(lo, __shfl_xor(lo, 1)); hi = fmaxf(hi, __shfl_xor(hi, 1));
            lo = fminf(lo, __shfl_xor(lo, 2)); hi = fmaxf(hi, __shfl_xor(hi, 2));
            lo = fminf(lo, __shfl_xor(lo, 4)); hi = fmaxf(hi, __shfl_xor(hi, 4));
            lo = fminf(lo, __shfl_xor(lo, 8)); hi = fmaxf(hi, __shfl_xor(hi, 8));
            if (l16 == 0) {
                const long long o = ((long long)b * M + grow) * 8 + by;
                aux0[o] = lo; aux1[o] = hi;
            }
        }
    }

    if constexpr (EPI == 4) {
        // f_sim never stored: emit row/col LSE partials + diagonal.
        float bn[NF];
        #pragma unroll
        for (int ni = 0; ni < NF; ++ni)
            bn[ni] = invn[(long long)b * N + n0 + 16 * ni + l16] * scale;
        float amv[MI * 4];
        #pragma unroll
        for (int mi = 0; mi < MI; ++mi)
            #pragma unroll
            for (int r = 0; r < 4; ++r)
                amv[mi * 4 + r] = invm[(long long)b * M + m0 + RPW * w + 16 * mi + quad * 4 + r];

        // row pass: lse over this block's NT cols, reduce across l16
        #pragma unroll
        for (int mi = 0; mi < MI; ++mi)
            #pragma unroll
            for (int r = 0; r < 4; ++r) {
                const int grow = m0 + RPW * w + 16 * mi + quad * 4 + r;
                float vv[NF];
                float rm = -1e30f;
                #pragma unroll
                for (int ni = 0; ni < NF; ++ni) {
                    const float v = acc[mi][ni][r] * amv[mi * 4 + r] * bn[ni];
                    vv[ni] = v;
                    rm = fmaxf(rm, v);
                    if (grow == n0 + 16 * ni + l16)
                        aux4[(long long)b * M + grow] = v;
                }
                #pragma unroll
                for (int o = 8; o > 0; o >>= 1) rm = fmaxf(rm, __shfl_xor(rm, o));
                float rs = 0.f;
                #pragma unroll
                for (int ni = 0; ni < NF; ++ni) rs += expf(vv[ni] - rm);
                #pragma unroll
                for (int o = 8; o > 0; o >>= 1) rs += __shfl_xor(rs, o);
                if (l16 == 0) {
                    const long long o = ((long long)b * M + grow) * 4 + by;
                    aux0[o] = rm; aux1[o] = rs;
                }
            }

        // col pass: lse over this block's 128 rows, reduce across quads + waves
        #pragma unroll
        for (int ni = 0; ni < NF; ++ni) {
            float va[MI * 4];
            float cm = -1e30f;
            #pragma unroll
            for (int mi = 0; mi < MI; ++mi)
                #pragma unroll
                for (int r = 0; r < 4; ++r) {
                    const float v = acc[mi][ni][r] * amv[mi * 4 + r] * bn[ni];
                    va[mi * 4 + r] = v;
                    cm = fmaxf(cm, v);
                }
            cm = fmaxf(cm, __shfl_xor(cm, 16));
            cm = fmaxf(cm, __shfl_xor(cm, 32));
            float cs = 0.f;
            #pragma unroll
            for (int j = 0; j < MI * 4; ++j) cs += expf(va[j] - cm);
            cs += __shfl_xor(cs, 16);
            cs += __shfl_xor(cs, 32);
            if (quad == 0) {
                redm[w * NT + 16 * ni + l16] = cm;
                reds[w * NT + 16 * ni + l16] = cs;
            }
        }
        __syncthreads();
        if (tid < NT) {
            float m = -1e30f, s = 0.f;
            #pragma unroll
            for (int w4 = 0; w4 < NW; ++w4) {
                const float cm = redm[w4 * NT + tid], cs = reds[w4 * NT + tid];
                const float nm = fmaxf(m, cm);
                s = s * expf(m - nm) + cs * expf(cm - nm);
                m = nm;
            }
            const long long o = ((long long)b * N + n0 + tid) * 4 + bx;
            aux2[o] = m; aux3[o] = s;
        }
    }
}

// =====================  small kernels  =====================

__global__ __launch_bounds__(256) void convert_w_k(
    const float* Wv, const float* Wt, us* Wvh, us* Wvl, us* Wth, us* Wtl)
{
    const int i = blockIdx.x * 256 + threadIdx.x;
    split_bf(Wv[i], Wvh[i], Wvl[i]);
    split_bf(Wt[i], Wth[i], Wtl[i]);
}

__global__ __launch_bounds__(256) void mean_img_k(
    const float* __restrict__ img, float* __restrict__ mimg)
{
    const int row = blockIdx.x * 4 + (threadIdx.x >> 6);
    const int lane = threadIdx.x & 63;
    const float* p = img + (long long)row * 1024;
    float s = 0.f;
    #pragma unroll
    for (int c = 0; c < 4; ++c) {
        float4 v = *(const float4*)&p[(c * 64 + lane) * 4];
        s += v.x + v.y + v.z + v.w;
    }
    #pragma unroll
    for (int o = 32; o > 0; o >>= 1) s += __shfl_xor(s, o);
    if (lane == 0) mimg[row] = s * (1.0f / 1024.0f);
}

__global__ __launch_bounds__(256) void mean_text_s1(
    const float* __restrict__ text, float* __restrict__ part)
{
    const int b = blockIdx.x, ch = blockIdx.y, k = threadIdx.x;
    const float* p = text + ((long long)b * 512 + ch * 64) * 256 + k;
    float s = 0.f;
    for (int r = 0; r < 64; ++r) s += p[r * 256];
    part[(b * 8 + ch) * 256 + k] = s;
}
__global__ __launch_bounds__(256) void mean_text_s2(
    const float* __restrict__ part, float* __restrict__ mt)
{
    const int b = blockIdx.x, k = threadIdx.x;
    float s = 0.f;
    for (int c = 0; c < 8; ++c) s += part[(b * 8 + c) * 256 + k];
    mt[b * 256 + k] = s * (1.0f / 512.0f);
}

__global__ __launch_bounds__(256) void small_adapter_k(
    const float* __restrict__ x, const float* __restrict__ W,
    const float* __restrict__ bias, float* __restrict__ y)
{
    const int b = blockIdx.x, d = threadIdx.x;
    __shared__ float xs[256];
    xs[d] = x[b * 256 + d];
    __syncthreads();
    const float4* w = (const float4*)(W + (long long)d * 256);
    const float4* xv = (const float4*)xs;
    float s = bias[d];
    #pragma unroll 8
    for (int k = 0; k < 64; ++k) {
        const float4 a = xv[k], ww = w[k];
        s += a.x * ww.x + a.y * ww.y + a.z * ww.z + a.w * ww.w;
    }
    y[b * 256 + d] = s;
}

// ---- parallelized global loss ----

__global__ __launch_bounds__(256) void inv_norm_f32_k(
    const float* __restrict__ x, float* __restrict__ inv)
{
    const int row = blockIdx.x * 4 + (threadIdx.x >> 6);
    const int lane = threadIdx.x & 63;
    float4 v = *(const float4*)&x[(long long)row * 256 + lane * 4];
    float s = v.x * v.x + v.y * v.y + v.z * v.z + v.w * v.w;
    #pragma unroll
    for (int o = 32; o > 0; o >>= 1) s += __shfl_xor(s, o);
    if (lane == 0) inv[row] = 1.0f / fmaxf(sqrtf(s), 1e-8f);
}

__global__ __launch_bounds__(256) void g_sim_k(
    const float* __restrict__ gi, const float* __restrict__ gt,
    const float* __restrict__ invI, const float* __restrict__ invT,
    float* __restrict__ gs)
{
    const int i = blockIdx.x, t = threadIdx.x;
    const int j = t >> 2, part = t & 3;
    __shared__ float a[256];
    a[t] = gi[i * 256 + t];
    __syncthreads();
    const float* bp = gt + (long long)j * 256 + part * 64;
    const float* ap = a + part * 64;
    float s = 0.f;
    #pragma unroll 16
    for (int k = 0; k < 64; ++k) s += ap[k] * bp[k];
    s += __shfl_xor(s, 1);
    s += __shfl_xor(s, 2);
    if (part == 0) gs[i * 64 + j] = s * invI[i] * invT[j] * TAU_INV;
}

__global__ __launch_bounds__(64) void g_lse_k(
    const float* __restrict__ gs, float* __restrict__ out)
{
    const int b = blockIdx.x, lane = threadIdx.x;
    const bool is_col = b >= 64;
    const int r = is_col ? b - 64 : b;
    const float v = is_col ? gs[lane * 64 + r] : gs[r * 64 + lane];
    float m = v;
    #pragma unroll
    for (int o = 32; o > 0; o >>= 1) m = fmaxf(m, __shfl_xor(m, o));
    float s = expf(v - m);
    #pragma unroll
    for (int o = 32; o > 0; o >>= 1) s += __shfl_xor(s, o);
    if (lane == 0)
        atomicAdd(out, ((m + logf(s)) - gs[r * 64 + r]) * (0.5f / 64.0f));
}

// inv L2 norm of 256-wide single-bf16 rows
__global__ __launch_bounds__(256) void inv_norm_b16_k(
    const us* __restrict__ x, float* __restrict__ inv)
{
    const int row = blockIdx.x * 4 + (threadIdx.x >> 6);
    const int lane = threadIdx.x & 63;
    ushort4 h = *(const ushort4*)&x[(long long)row * 256 + lane * 4];
    const float x0 = bf2f(h.x), x1 = bf2f(h.y), x2 = bf2f(h.z), x3 = bf2f(h.w);
    float s = x0 * x0 + x1 * x1 + x2 * x2 + x3 * x3;
    #pragma unroll
    for (int o = 32; o > 0; o >>= 1) s += __shfl_xor(s, o);
    if (lane == 0) inv[row] = 1.0f / fmaxf(sqrtf(s), 1e-8f);
}

// ---- merge kernels ----

// merge 8 minmax partials per (b,s); grid 128 x 256
__global__ __launch_bounds__(256) void minmax_merge_k(
    const float* __restrict__ mnp, const float* __restrict__ mxp,
    float* __restrict__ mn, float* __restrict__ mx)
{
    const int idx = blockIdx.x * 256 + threadIdx.x;
    float lo = 1e30f, hi = -1e30f;
    #pragma unroll
    for (int c = 0; c < 8; ++c) {
        lo = fminf(lo, mnp[(long long)idx * 8 + c]);
        hi = fmaxf(hi, mxp[(long long)idx * 8 + c]);
    }
    mn[idx] = lo; mx[idx] = hi;
}

// merge 4 LSE partials per row/col, subtract diag; grid 128 x 256
__global__ __launch_bounds__(256) void fine_merge4_k(
    const float* __restrict__ pm, const float* __restrict__ ps,
    const float* __restrict__ diag, float* __restrict__ out)
{
    const int idx = blockIdx.x * 256 + threadIdx.x;
    float m = -1e30f, s = 0.f;
    #pragma unroll
    for (int c = 0; c < 4; ++c) {
        const float cm = pm[(long long)idx * 4 + c], cs = ps[(long long)idx * 4 + c];
        const float nm = fmaxf(m, cm);
        s = s * expf(m - nm) + cs * expf(cm - nm);
        m = nm;
    }
    const float contrib = (m + logf(s)) - diag[idx];
    __shared__ float red[256];
    red[threadIdx.x] = contrib;
    __syncthreads();
    for (int w = 128; w > 0; w >>= 1) {
        if (threadIdx.x < w) red[threadIdx.x] += red[threadIdx.x + w];
        __syncthreads();
    }
    if (threadIdx.x == 0) atomicAdd(out, red[0] * (0.5f / (64.0f * 512.0f)));
}

extern "C" void kernel_launch(void* const* d_in, const int* in_sizes, int n_in,
                              void* d_out, int out_size, void* d_ws, size_t ws_size,
                              hipStream_t stream)
{
    const float* img  = (const float*)d_in[0];
    const float* text = (const float*)d_in[1];
    const float* Wv   = (const float*)d_in[2];
    const float* bv   = (const float*)d_in[3];
    const float* Wt   = (const float*)d_in[4];
    const float* bt   = (const float*)d_in[5];
    float* out = (float*)d_out;
    char* ws = (char*)d_ws;

    us* patches = (us*)(ws + 0);              // 33,554,432 B
    us* tokens  = (us*)(ws + 33554432);       // 16,777,216 B
    us* simT    = (us*)(ws + 50331648);       // 67,108,864 B  (now [b][s][p])
    us* lgve    = (us*)(ws + 117440512);      // 16,777,216 B
    char* st = ws + 134217728;
    float* mean_img  = (float*)(st + 0);
    float* mean_text = (float*)(st + 65536);
    float* mean_pat  = (float*)(st + 131072);
    float* mean_tok  = (float*)(st + 196608);
    float* g_img     = (float*)(st + 262144);
    float* g_txt     = (float*)(st + 327680);
    float* textpart  = (float*)(st + 393216);
    float* mnp       = (float*)(st + 917504);   // 1 MB
    float* mxp       = (float*)(st + 1966080);  // 1 MB
    float* mnv       = (float*)(st + 3014656);
    float* mxv       = (float*)(st + 3145728);
    float* inv_l     = (float*)(st + 3276800);
    float* inv_t     = (float*)(st + 3407872);
    us* Wvh = (us*)(st + 3538944);
    us* Wvl = (us*)(st + 3670016);
    us* Wth = (us*)(st + 3801088);
    us* Wtl = (us*)(st + 3932160);
    float* inv_gi  = (float*)(st + 4063232);
    float* inv_gt  = (float*)(st + 4063744);
    float* g_simbf = (float*)(st + 4064256);
    float* pm_row  = (float*)(st + 4194304);   // 512 KB (4 partials/row)
    float* ps_row  = (float*)(st + 4718592);   // 512 KB
    float* pm_col  = (float*)(st + 5242880);   // 512 KB
    float* ps_col  = (float*)(st + 5767168);   // 512 KB
    float* diag    = (float*)(st + 6291456);   // 128 KB

    zero_out_k<<<1, 64, 0, stream>>>(out);
    convert_w_k<<<256, 256, 0, stream>>>(Wv, Wt, Wvh, Wvl, Wth, Wtl);

    // Global path (mean commutes with linear)
    mean_img_k<<<4096, 256, 0, stream>>>(img, mean_img);
    mean_text_s1<<<dim3(64, 8), 256, 0, stream>>>(text, textpart);
    mean_text_s2<<<64, 256, 0, stream>>>(textpart, mean_text);
    small_adapter_k<<<BB, 256, 0, stream>>>(mean_img, Wv, bv, mean_pat);
    small_adapter_k<<<BB, 256, 0, stream>>>(mean_pat, Wv, bv, g_img);
    small_adapter_k<<<BB, 256, 0, stream>>>(mean_text, Wt, bt, mean_tok);
    small_adapter_k<<<BB, 256, 0, stream>>>(mean_tok, Wt, bt, g_txt);
    inv_norm_f32_k<<<16, 256, 0, stream>>>(g_img, inv_gi);
    inv_norm_f32_k<<<16, 256, 0, stream>>>(g_txt, inv_gt);
    g_sim_k<<<64, 256, 0, stream>>>(g_img, g_txt, inv_gi, inv_gt, g_simbf);
    g_lse_k<<<128, 64, 0, stream>>>(g_simbf, out);

    // G1: patches = img.Wv + bv (split internally, bf16 out; NT=256 -> img x1)
    mfma_gemm<OPM_F32_COL, OPM_SPL_ROW, OUT_B16, 1, 256, 0, 4, 0><<<dim3(8, 1, BB), 256, 0, stream>>>(
        img, nullptr, Wvh, Wvl, patches,
        1024, 256, 256, 1024, 256, 256,
        1048576LL, 0LL, 524288LL, bv, nullptr, nullptr, 0.f, nullptr, nullptr,
        nullptr, nullptr, nullptr, nullptr, nullptr);

    // G2: tokens = text.Wt + bt
    mfma_gemm<OPM_F32_ROW, OPM_SPL_ROW, OUT_B16, 1, 256, 0, 4, 0><<<dim3(4, 1, BB), 256, 0, stream>>>(
        text, nullptr, Wth, Wtl, tokens,
        512, 256, 256, 256, 256, 256,
        524288LL, 0LL, 262144LL, bt, nullptr, nullptr, 0.f, nullptr, nullptr,
        nullptr, nullptr, nullptr, nullptr, nullptr);

    // G4': simT = tokens . patches^T  (same dot products as sim, transposed
    // output layout), DMA-staged, row-minmax fused.
    mfma_gemm<OPM_B16_ROW, OPM_B16_ROW, OUT_B16, 3, 128, 0, 8, 1><<<dim3(4, 8, BB), 512, 0, stream>>>(
        tokens, nullptr, patches, nullptr, simT,
        512, 1024, 256, 256, 256, 1024,
        262144LL, 524288LL, 1048576LL, nullptr, nullptr, nullptr, 0.f, nullptr, nullptr,
        mnp, mxp, nullptr, nullptr, nullptr);

    minmax_merge_k<<<128, 256, 0, stream>>>(mnp, mxp, mnv, mxv);

    // G6: lgve = w.patches; A = simT row-wise + fused weight transform,
    // B = patches col (scalar), reg-staged path.
    mfma_gemm<OPM_WGT_ROW, OPM_B16_COL, OUT_B16, 0, 128, 1, 8, 0><<<dim3(4, 2, BB), 512, 0, stream>>>(
        simT, nullptr, patches, nullptr, lgve,
        512, 256, 1024, 1024, 256, 256,
        1048576LL, 524288LL, 262144LL, nullptr, nullptr, nullptr, 0.f, mnv, mxv,
        nullptr, nullptr, nullptr, nullptr, nullptr);

    inv_norm_b16_k<<<8192, 256, 0, stream>>>(lgve, inv_l);
    inv_norm_b16_k<<<8192, 256, 0, stream>>>(tokens, inv_t);

    // G8: f_sim never materialized; DMA-staged, 4 row + 4 col LSE partials
    mfma_gemm<OPM_B16_ROW, OPM_B16_ROW, OUT_B16, 4, 128, 0, 8, 1><<<dim3(4, 4, BB), 512, 0, stream>>>(
        lgve, nullptr, tokens, nullptr, nullptr,
        512, 512, 256, 256, 256, 512,
        262144LL, 262144LL, 0LL, nullptr, inv_l, inv_t, TAU_INV, nullptr, nullptr,
        pm_row, ps_row, pm_col, ps_col, diag);

    fine_merge4_k<<<128, 256, 0, stream>>>(pm_row, ps_row, diag, out);
    fine_merge4_k<<<128, 256, 0, stream>>>(pm_col, ps_col, diag, out);
}

// Round 6
// 383.941 us; speedup vs baseline: 1.0310x; 1.0301x over previous
//
#include <hip/hip_runtime.h>
#include <math.h>

#define BB   64
#define HWP  1024
#define SS   512
#define DD   256
#define TAU_INV (1.0f/0.07f)
#define SIGMA   (1.0f/1024.0f)

typedef unsigned short us;
typedef __attribute__((ext_vector_type(8))) short short8v;
typedef __attribute__((ext_vector_type(8))) unsigned short ushort8v;
typedef __attribute__((ext_vector_type(4))) float floatx4;

__device__ __forceinline__ float bf2f(us u) {
    return __uint_as_float((unsigned)u << 16);
}
__device__ __forceinline__ us f2bf(float f) {
    unsigned u = __float_as_uint(f);
    u += 0x7FFFu + ((u >> 16) & 1u);
    return (us)(u >> 16);
}
__device__ __forceinline__ void split_bf(float v, us& h, us& l) {
    h = f2bf(v);
    l = f2bf(v - bf2f(h));
}

// R15: HBM->LDS DMA, bypasses VGPRs entirely (regalloc cannot sink it).
__device__ __forceinline__ void dma16(const us* g, us* l) {
    __builtin_amdgcn_global_load_lds(
        (const __attribute__((address_space(1))) unsigned int*)g,
        (__attribute__((address_space(3))) unsigned int*)l, 16, 0, 0);
}

__global__ void zero_out_k(float* out) { if (threadIdx.x == 0) out[0] = 0.0f; }

// =====================  MFMA GEMM  =====================
// C[m,n] = sum_k A(m,k)*B(n,k). Tile 128 x NT, BK=32, 16x16x32 bf16 MFMA.
// R15: G4'/G8 via global_load_lds double-buffered linear LDS + vmcnt(2)
//      pipeline (worked: both left top-5). G6: WGT_ROW A + scalar-COL B.
// R16: G1 surfaced as the new top (52.9us, Occupancy 9.9%!). Cause: NW4 path
//      with NT=256 -> acc alone is 128 VGPR (VGPR_Count 184 -> 2 waves/SIMD),
//      plus 16 scalar f32 loads + 16 split_bf serial chain per thread per
//      k-step with nothing resident to overlap it. G1/G2 -> NW=8: acc 64
//      VGPR, per-thread staging halves, 2 blocks x 8 waves = 16 waves/CU.
//      (G1 cannot use DMA: it must convert f32 -> split-bf16 in registers.)
enum { OPM_F32_ROW = 0, OPM_F32_COL = 1, OPM_SPL_ROW = 2, OPM_SPL_COL = 3,
       OPM_B16_COL = 4, OPM_B16_ROW = 5, OPM_WGT_COL = 6, OPM_WGT_ROW = 7 };
enum { OUT_F32 = 0, OUT_B16 = 1 };

#define LDSTRIDE 40

template<int MODE, int ROWS, int NW>
struct SRegs {
    static constexpr int RR = ROWS / 128;
    static constexpr bool ISF32 = (MODE == OPM_F32_ROW) || (MODE == OPM_F32_COL);
    ushort8v h[ISF32 ? 1 : RR][2];     // NW==8 paths use [rr][0] only (DCE'd)
    ushort8v l[(MODE == OPM_SPL_ROW) ? RR : 1][2];
    float4   f[ISF32 ? RR : 1][4];     // NW==8 F32 paths use f[0][0..1] only
};

// global -> registers (raw data, no conversion math)
template<int MODE, int ROWS, int NW>
__device__ __forceinline__ void stage_load(
    const char* p0, const char* p1, int ld, int row0, int k0, int tid,
    SRegs<MODE, ROWS, NW>& R)
{
    #pragma unroll
    for (int rr = 0; rr < ROWS / 128; ++rr) {
        if constexpr (MODE == OPM_SPL_ROW) {
            const us* ph = (const us*)p0;
            const us* pl = (const us*)p1;
            if constexpr (NW == 4) {
                const int i = rr * 128 + (tid >> 1), ko = (tid & 1) * 16;
                const long long g = (long long)(row0 + i) * ld + k0 + ko;
                R.h[rr][0] = *(const ushort8v*)&ph[g];
                R.h[rr][1] = *(const ushort8v*)&ph[g + 8];
                R.l[rr][0] = *(const ushort8v*)&pl[g];
                R.l[rr][1] = *(const ushort8v*)&pl[g + 8];
            } else {
                // R16: 512 threads -> 8 elems each (h + l planes)
                const int i = rr * 128 + (tid >> 2), ko = (tid & 3) * 8;
                const long long g = (long long)(row0 + i) * ld + k0 + ko;
                R.h[rr][0] = *(const ushort8v*)&ph[g];
                R.l[rr][0] = *(const ushort8v*)&pl[g];
            }
        } else if constexpr (MODE == OPM_B16_ROW || MODE == OPM_WGT_ROW) {
            const us* ph = (const us*)p0;
            if constexpr (NW == 4) {
                const int i = rr * 128 + (tid >> 1), ko = (tid & 1) * 16;
                const long long g = (long long)(row0 + i) * ld + k0 + ko;
                R.h[rr][0] = *(const ushort8v*)&ph[g];
                R.h[rr][1] = *(const ushort8v*)&ph[g + 8];
            } else {
                const int i = rr * 128 + (tid >> 2), ko = (tid & 3) * 8;
                const long long g = (long long)(row0 + i) * ld + k0 + ko;
                R.h[rr][0] = *(const ushort8v*)&ph[g];
            }
        } else if constexpr (MODE == OPM_F32_ROW) {
            const float* pf = (const float*)p0;
            if constexpr (NW == 4) {
                const int i = rr * 128 + (tid >> 1), ko = (tid & 1) * 16;
                const long long g = (long long)(row0 + i) * ld + k0 + ko;
                #pragma unroll
                for (int c = 0; c < 4; ++c)
                    R.f[rr][c] = *(const float4*)&pf[g + c * 4];
            } else {
                // R16: 8 f32 per thread
                const int i = rr * 128 + (tid >> 2), ko = (tid & 3) * 8;
                const long long g = (long long)(row0 + i) * ld + k0 + ko;
                R.f[rr][0] = *(const float4*)&pf[g];
                R.f[rr][1] = *(const float4*)&pf[g + 4];
            }
        } else if constexpr (MODE == OPM_F32_COL) {
            const float* pf = (const float*)p0;
            if constexpr (NW == 4) {
                const int m = rr * 128 + (tid & 127), kh = (tid >> 7) * 16;
                const long long base = (long long)(k0 + kh) * ld + row0 + m;
                #pragma unroll
                for (int c = 0; c < 4; ++c) {
                    float4 v;
                    v.x = pf[base + (long long)(c * 4 + 0) * ld];
                    v.y = pf[base + (long long)(c * 4 + 1) * ld];
                    v.z = pf[base + (long long)(c * 4 + 2) * ld];
                    v.w = pf[base + (long long)(c * 4 + 3) * ld];
                    R.f[rr][c] = v;
                }
            } else {
                // R16: 8 scalar column loads per thread (coalesced across m)
                const int m = rr * 128 + (tid & 127), kh = (tid >> 7) * 8;
                const long long base = (long long)(k0 + kh) * ld + row0 + m;
                #pragma unroll
                for (int c = 0; c < 2; ++c) {
                    float4 v;
                    v.x = pf[base + (long long)(c * 4 + 0) * ld];
                    v.y = pf[base + (long long)(c * 4 + 1) * ld];
                    v.z = pf[base + (long long)(c * 4 + 2) * ld];
                    v.w = pf[base + (long long)(c * 4 + 3) * ld];
                    R.f[rr][c] = v;
                }
            }
        } else if constexpr (MODE == OPM_B16_COL) {
            const us* ph = (const us*)p0;
            if constexpr (NW == 4) {
                const int m = rr * 128 + (tid & 127), kh = (tid >> 7) * 16;
                const long long base = (long long)(k0 + kh) * ld + row0 + m;
                #pragma unroll
                for (int kk = 0; kk < 8; ++kk) {
                    R.h[rr][0][kk] = ph[base + (long long)kk * ld];
                    R.h[rr][1][kk] = ph[base + (long long)(kk + 8) * ld];
                }
            } else {
                const int m = rr * 128 + (tid & 127), kh = (tid >> 7) * 8;
                const long long base = (long long)(k0 + kh) * ld + row0 + m;
                #pragma unroll
                for (int kk = 0; kk < 8; ++kk)
                    R.h[rr][0][kk] = ph[base + (long long)kk * ld];
            }
        }
    }
}

// registers -> LDS (conversion / weight math happens here)
template<int MODE, int ROWS, int NW>
__device__ __forceinline__ void stage_store(
    const SRegs<MODE, ROWS, NW>& R, us* ldsH, us* ldsL, int tid, float nlo, float inv)
{
    #pragma unroll
    for (int rr = 0; rr < ROWS / 128; ++rr) {
        if constexpr (MODE == OPM_SPL_ROW) {
            if constexpr (NW == 4) {
                const int i = rr * 128 + (tid >> 1), ko = (tid & 1) * 16;
                *(ushort8v*)&ldsH[i * LDSTRIDE + ko]     = R.h[rr][0];
                *(ushort8v*)&ldsH[i * LDSTRIDE + ko + 8] = R.h[rr][1];
                *(ushort8v*)&ldsL[i * LDSTRIDE + ko]     = R.l[rr][0];
                *(ushort8v*)&ldsL[i * LDSTRIDE + ko + 8] = R.l[rr][1];
            } else {
                const int i = rr * 128 + (tid >> 2), ko = (tid & 3) * 8;
                *(ushort8v*)&ldsH[i * LDSTRIDE + ko] = R.h[rr][0];
                *(ushort8v*)&ldsL[i * LDSTRIDE + ko] = R.l[rr][0];
            }
        } else if constexpr (MODE == OPM_B16_ROW) {
            if constexpr (NW == 4) {
                const int i = rr * 128 + (tid >> 1), ko = (tid & 1) * 16;
                *(ushort8v*)&ldsH[i * LDSTRIDE + ko]     = R.h[rr][0];
                *(ushort8v*)&ldsH[i * LDSTRIDE + ko + 8] = R.h[rr][1];
            } else {
                const int i = rr * 128 + (tid >> 2), ko = (tid & 3) * 8;
                *(ushort8v*)&ldsH[i * LDSTRIDE + ko] = R.h[rr][0];
            }
        } else if constexpr (MODE == OPM_WGT_ROW) {
            // R15c: row-staged simT + uniform per-row weight transform (NW8)
            const int i = tid >> 2, ko = (tid & 3) * 8;
            us v[8];
            #pragma unroll
            for (int j = 0; j < 8; ++j) {
                const float w0 = fmaf(bf2f(R.h[0][0][j]), inv, nlo);
                v[j] = (w0 < SIGMA) ? (us)0 : f2bf(w0);
            }
            *(ushort8v*)&ldsH[i * LDSTRIDE + ko] = *(const ushort8v*)&v[0];
        } else if constexpr (MODE == OPM_F32_ROW) {
            if constexpr (NW == 4) {
                const int i = rr * 128 + (tid >> 1), ko = (tid & 1) * 16;
                us h16[16], l16a[16];
                #pragma unroll
                for (int c = 0; c < 4; ++c) {
                    float4 v = R.f[rr][c];
                    split_bf(v.x, h16[c*4+0], l16a[c*4+0]);
                    split_bf(v.y, h16[c*4+1], l16a[c*4+1]);
                    split_bf(v.z, h16[c*4+2], l16a[c*4+2]);
                    split_bf(v.w, h16[c*4+3], l16a[c*4+3]);
                }
                *(ushort8v*)&ldsH[i * LDSTRIDE + ko]     = *(const ushort8v*)&h16[0];
                *(ushort8v*)&ldsH[i * LDSTRIDE + ko + 8] = *(const ushort8v*)&h16[8];
                *(ushort8v*)&ldsL[i * LDSTRIDE + ko]     = *(const ushort8v*)&l16a[0];
                *(ushort8v*)&ldsL[i * LDSTRIDE + ko + 8] = *(const ushort8v*)&l16a[8];
            } else {
                const int i = rr * 128 + (tid >> 2), ko = (tid & 3) * 8;
                us h8[8], l8[8];
                #pragma unroll
                for (int c = 0; c < 2; ++c) {
                    float4 v = R.f[rr][c];
                    split_bf(v.x, h8[c*4+0], l8[c*4+0]);
                    split_bf(v.y, h8[c*4+1], l8[c*4+1]);
                    split_bf(v.z, h8[c*4+2], l8[c*4+2]);
                    split_bf(v.w, h8[c*4+3], l8[c*4+3]);
                }
                *(ushort8v*)&ldsH[i * LDSTRIDE + ko] = *(const ushort8v*)&h8[0];
                *(ushort8v*)&ldsL[i * LDSTRIDE + ko] = *(const ushort8v*)&l8[0];
            }
        } else if constexpr (MODE == OPM_F32_COL) {
            if constexpr (NW == 4) {
                const int m = rr * 128 + (tid & 127), kh = (tid >> 7) * 16;
                us vh[16], vl[16];
                #pragma unroll
                for (int c = 0; c < 4; ++c) {
                    float4 v = R.f[rr][c];
                    split_bf(v.x, vh[c*4+0], vl[c*4+0]);
                    split_bf(v.y, vh[c*4+1], vl[c*4+1]);
                    split_bf(v.z, vh[c*4+2], vl[c*4+2]);
                    split_bf(v.w, vh[c*4+3], vl[c*4+3]);
                }
                *(ushort8v*)&ldsH[m * LDSTRIDE + kh]     = *(const ushort8v*)&vh[0];
                *(ushort8v*)&ldsH[m * LDSTRIDE + kh + 8] = *(const ushort8v*)&vh[8];
                *(ushort8v*)&ldsL[m * LDSTRIDE + kh]     = *(const ushort8v*)&vl[0];
                *(ushort8v*)&ldsL[m * LDSTRIDE + kh + 8] = *(const ushort8v*)&vl[8];
            } else {
                const int m = rr * 128 + (tid & 127), kh = (tid >> 7) * 8;
                us vh[8], vl[8];
                #pragma unroll
                for (int c = 0; c < 2; ++c) {
                    float4 v = R.f[rr][c];
                    split_bf(v.x, vh[c*4+0], vl[c*4+0]);
                    split_bf(v.y, vh[c*4+1], vl[c*4+1]);
                    split_bf(v.z, vh[c*4+2], vl[c*4+2]);
                    split_bf(v.w, vh[c*4+3], vl[c*4+3]);
                }
                *(ushort8v*)&ldsH[m * LDSTRIDE + kh] = *(const ushort8v*)&vh[0];
                *(ushort8v*)&ldsL[m * LDSTRIDE + kh] = *(const ushort8v*)&vl[0];
            }
        } else if constexpr (MODE == OPM_B16_COL) {
            if constexpr (NW == 4) {
                const int m = rr * 128 + (tid & 127), kh = (tid >> 7) * 16;
                us v[16];
                #pragma unroll
                for (int kk = 0; kk < 16; ++kk)
                    v[kk] = (kk < 8) ? R.h[rr][0][kk & 7] : R.h[rr][1][kk & 7];
                *(ushort8v*)&ldsH[m * LDSTRIDE + kh]     = *(const ushort8v*)&v[0];
                *(ushort8v*)&ldsH[m * LDSTRIDE + kh + 8] = *(const ushort8v*)&v[8];
            } else {
                const int m = rr * 128 + (tid & 127), kh = (tid >> 7) * 8;
                *(ushort8v*)&ldsH[m * LDSTRIDE + kh] = R.h[rr][0];
            }
        }
    }
}

template<int AMODE, int BMODE, int OMODE, int EPI, int NT, int PREF, int NW, int DMA>
__global__ __launch_bounds__(NW * 64) void mfma_gemm(
    const void* A0, const void* A1, const void* B0, const void* B1, void* C0,
    int M, int N, int K, int lda, int ldb, int ldc,
    long long sA, long long sB, long long sC,
    const float* __restrict__ bias, const float* __restrict__ invm,
    const float* __restrict__ invn, float scale,
    const float* __restrict__ wlo, const float* __restrict__ whi,
    float* __restrict__ aux0, float* __restrict__ aux1,
    float* __restrict__ aux2, float* __restrict__ aux3, float* __restrict__ aux4)
{
    constexpr bool ASPL = (AMODE <= OPM_SPL_COL);
    constexpr bool BSPL = (BMODE <= OPM_SPL_COL);
    constexpr int NF = NT / 16;
    constexpr int MI = 8 / NW;         // 16-row frags per wave (2 @NW4, 1 @NW8)
    constexpr int RPW = 128 / NW;      // rows per wave
    __shared__ __align__(16) us Ah[DMA ? 8 : 128 * LDSTRIDE];
    __shared__ __align__(16) us Al[(!DMA && ASPL) ? 128 * LDSTRIDE : 8];
    __shared__ __align__(16) us Bh[DMA ? 8 : NT * LDSTRIDE];
    __shared__ __align__(16) us Bl[(!DMA && BSPL) ? NT * LDSTRIDE : 8];
    __shared__ __align__(16) us AhD[DMA ? 2 * 128 * 32 : 8];   // linear, dbuf
    __shared__ __align__(16) us BhD[DMA ? 2 * NT * 32 : 8];
    __shared__ float redm[(EPI == 4) ? NW * NT : 1];
    __shared__ float reds[(EPI == 4) ? NW * NT : 1];

    const int tid = threadIdx.x;
    const int w = tid >> 6, lane = tid & 63;
    const int quad = lane >> 4, l16 = lane & 15;

    // XCD-chunked bijective swizzle (nwg % 8 == 0 for all grids here).
    int bx = blockIdx.x, by = blockIdx.y, bz = blockIdx.z;
    {
        const int nbx = gridDim.x, nby = gridDim.y, nbz = gridDim.z;
        const int nwg = nbx * nby * nbz;
        if ((nwg & 7) == 0) {
            const int hw = bx + nbx * (by + nby * bz);
            const int cpx = nwg >> 3;
            int wk = (hw & 7) * cpx + (hw >> 3);
            bx = wk % nbx; wk /= nbx;
            by = wk % nby; bz = wk / nby;
        }
    }

    const int m0 = bx * 128, n0 = by * NT;
    const int b = bz;

    const char* Ab0 = (const char*)A0 + (long long)b * sA;
    const char* Ab1 = A1 ? (const char*)A1 + (long long)b * sA : nullptr;
    const char* Bb0 = (const char*)B0 + (long long)b * sB;
    const char* Bb1 = B1 ? (const char*)B1 + (long long)b * sB : nullptr;

    floatx4 acc[MI][NF];
    #pragma unroll
    for (int mi = 0; mi < MI; ++mi)
        #pragma unroll
        for (int ni = 0; ni < NF; ++ni)
            acc[mi][ni] = (floatx4){0.f, 0.f, 0.f, 0.f};

    if constexpr (DMA) {
        // ================= R15a: DMA-staged pipeline (ROW/ROW only) =========
        const us* Abu = (const us*)Ab0;
        const us* Bbu = (const us*)Bb0;
        const int drow = 16 * w + (lane >> 2);
        const int dcol = (lane & 3) * 8;
        const us* aS = Abu + (long long)(m0 + drow) * lda + dcol;
        const us* bS = Bbu + (long long)(n0 + drow) * ldb + dcol;
        us* aD = &AhD[0] + 512 * w;
        us* bD = &BhD[0] + 512 * w;
        const int NTL = K >> 5;

        dma16(aS,      aD);
        dma16(bS,      bD);
        dma16(aS + 32, aD + 128 * 32);
        dma16(bS + 32, bD + NT * 32);

        int cur = 0;
        for (int t = 0; t < NTL; ++t) {
            if (t + 1 == NTL) asm volatile("s_waitcnt vmcnt(0)" ::: "memory");
            else              asm volatile("s_waitcnt vmcnt(2)" ::: "memory");
            __builtin_amdgcn_s_barrier();
            asm volatile("" ::: "memory");

            {
                const us* Ac = &AhD[cur * 128 * 32];
                const us* Bc = &BhD[cur * NT * 32];
                short8v ah = *(const short8v*)&Ac[(16 * w + l16) * 32 + quad * 8];
                #pragma unroll
                for (int ni = 0; ni < NF; ++ni) {
                    short8v bh = *(const short8v*)&Bc[(16 * ni + l16) * 32 + quad * 8];
                    acc[0][ni] = __builtin_amdgcn_mfma_f32_16x16x32_bf16(ah, bh, acc[0][ni], 0, 0, 0);
                }
            }

            asm volatile("" ::: "memory");
            __builtin_amdgcn_s_barrier();
            if (t + 2 < NTL) {
                const long long off = (long long)(t + 2) * 32;
                dma16(aS + off, aD + cur * 128 * 32);
                dma16(bS + off, bD + cur * NT * 32);
            }
            cur ^= 1;
        }
    } else {
        // ================= reg-staged path (G1/G2/G6) ======================
        float nloA = 0.f, invA = 0.f;
        if constexpr (AMODE == OPM_WGT_ROW) {
            const float* wloA = wlo + (long long)b * M;
            const float* whiA = whi + (long long)b * M;
            const int row = m0 + (tid >> 2);       // NW8 staging row
            const float lo = wloA[row];
            invA = 1.0f / (whiA[row] - lo + 1e-8f);
            nloA = -lo * invA;
        }

        SRegs<AMODE, 128, NW> RA0, RA1;
        SRegs<BMODE, NT, NW>  RB0, RB1;
        if constexpr (PREF) {
            stage_load<AMODE, 128, NW>(Ab0, Ab1, lda, m0, 0, tid, RA0);
            stage_load<BMODE, NT, NW>(Bb0, Bb1, ldb, n0, 0, tid, RB0);
            stage_load<AMODE, 128, NW>(Ab0, Ab1, lda, m0, 32, tid, RA1);
            stage_load<BMODE, NT, NW>(Bb0, Bb1, ldb, n0, 32, tid, RB1);
        }

        auto do_mfma = [&]() {
            short8v ah[MI], al[MI];
            #pragma unroll
            for (int mi = 0; mi < MI; ++mi) {
                const int r = (RPW * w + 16 * mi + l16) * LDSTRIDE + quad * 8;
                ah[mi] = *(const short8v*)&Ah[r];
                if constexpr (ASPL) al[mi] = *(const short8v*)&Al[r];
            }
            #pragma unroll
            for (int ni = 0; ni < NF; ++ni) {
                const int rB = (16 * ni + l16) * LDSTRIDE + quad * 8;
                short8v bh = *(const short8v*)&Bh[rB];
                #pragma unroll
                for (int mi = 0; mi < MI; ++mi)
                    acc[mi][ni] = __builtin_amdgcn_mfma_f32_16x16x32_bf16(ah[mi], bh, acc[mi][ni], 0, 0, 0);
                if constexpr (BSPL) {
                    short8v bl = *(const short8v*)&Bl[rB];
                    #pragma unroll
                    for (int mi = 0; mi < MI; ++mi)
                        acc[mi][ni] = __builtin_amdgcn_mfma_f32_16x16x32_bf16(ah[mi], bl, acc[mi][ni], 0, 0, 0);
                }
                if constexpr (ASPL) {
                    #pragma unroll
                    for (int mi = 0; mi < MI; ++mi)
                        acc[mi][ni] = __builtin_amdgcn_mfma_f32_16x16x32_bf16(al[mi], bh, acc[mi][ni], 0, 0, 0);
                }
            }
        };

#define GEMM_SUBSTEP(RAx, RBx, KCUR, KNEXT)                                    \
    do {                                                                       \
        if constexpr (!PREF) {                                                 \
            stage_load<AMODE, 128, NW>(Ab0, Ab1, lda, m0, (KCUR), tid, RAx);   \
            stage_load<BMODE, NT, NW>(Bb0, Bb1, ldb, n0, (KCUR), tid, RBx);    \
        }                                                                      \
        stage_store<AMODE, 128, NW>(RAx, Ah, Al, tid, nloA, invA);             \
        stage_store<BMODE, NT, NW>(RBx, Bh, Bl, tid, 0.f, 0.f);                \
        if constexpr (PREF) {                                                  \
            asm volatile("s_waitcnt lgkmcnt(0)" ::: "memory");                 \
            __builtin_amdgcn_s_barrier();                                      \
            if ((KNEXT) < K) {                                                 \
                stage_load<AMODE, 128, NW>(Ab0, Ab1, lda, m0, (KNEXT), tid, RAx); \
                stage_load<BMODE, NT, NW>(Bb0, Bb1, ldb, n0, (KNEXT), tid, RBx);  \
            }                                                                  \
        } else {                                                               \
            __syncthreads();                                                   \
        }                                                                      \
        do_mfma();                                                             \
        if constexpr (PREF) {                                                  \
            asm volatile("s_waitcnt lgkmcnt(0)" ::: "memory");                 \
            __builtin_amdgcn_s_barrier();                                      \
        } else {                                                               \
            __syncthreads();                                                   \
        }                                                                      \
    } while (0)

        for (int k0 = 0; k0 < K; k0 += 64) {
            GEMM_SUBSTEP(RA0, RB0, k0, k0 + 64);
            GEMM_SUBSTEP(RA1, RB1, k0 + 32, k0 + 96);
        }
#undef GEMM_SUBSTEP
    }

    if constexpr (EPI != 4) {
        char* Cb0 = (char*)C0 + (long long)b * sC;
        #pragma unroll
        for (int mi = 0; mi < MI; ++mi)
            #pragma unroll
            for (int ni = 0; ni < NF; ++ni)
                #pragma unroll
                for (int r = 0; r < 4; ++r) {
                    const int row = m0 + RPW * w + 16 * mi + quad * 4 + r;
                    const int col = n0 + 16 * ni + l16;
                    float v = acc[mi][ni][r];
                    if constexpr (EPI == 1) v += bias[col];
                    const long long idx = (long long)row * ldc + col;
                    if constexpr (OMODE == OUT_F32) ((float*)Cb0)[idx] = v;
                    else                            ((us*)Cb0)[idx] = f2bf(v);
                }
    }

    if constexpr (EPI == 3) {
        // R15b: ROW min/max of bf16-rounded stored values (C is simT[s][p]).
        #pragma unroll
        for (int r = 0; r < 4; ++r) {
            const int grow = m0 + RPW * w + quad * 4 + r;
            float lo = 1e30f, hi = -1e30f;
            #pragma unroll
            for (int ni = 0; ni < NF; ++ni) {
                const float vr = bf2f(f2bf(acc[0][ni][r]));
                lo = fminf(lo, vr); hi = fmaxf(hi, vr);
            }
            lo = fminf(lo, __shfl_xor(lo, 1)); hi = fmaxf(hi, __shfl_xor(hi, 1));
            lo = fminf(lo, __shfl_xor(lo, 2)); hi = fmaxf(hi, __shfl_xor(hi, 2));
            lo = fminf(lo, __shfl_xor(lo, 4)); hi = fmaxf(hi, __shfl_xor(hi, 4));
            lo = fminf(lo, __shfl_xor(lo, 8)); hi = fmaxf(hi, __shfl_xor(hi, 8));
            if (l16 == 0) {
                const long long o = ((long long)b * M + grow) * 8 + by;
                aux0[o] = lo; aux1[o] = hi;
            }
        }
    }

    if constexpr (EPI == 4) {
        // f_sim never stored: emit row/col LSE partials + diagonal.
        float bn[NF];
        #pragma unroll
        for (int ni = 0; ni < NF; ++ni)
            bn[ni] = invn[(long long)b * N + n0 + 16 * ni + l16] * scale;
        float amv[MI * 4];
        #pragma unroll
        for (int mi = 0; mi < MI; ++mi)
            #pragma unroll
            for (int r = 0; r < 4; ++r)
                amv[mi * 4 + r] = invm[(long long)b * M + m0 + RPW * w + 16 * mi + quad * 4 + r];

        // row pass: lse over this block's NT cols, reduce across l16
        #pragma unroll
        for (int mi = 0; mi < MI; ++mi)
            #pragma unroll
            for (int r = 0; r < 4; ++r) {
                const int grow = m0 + RPW * w + 16 * mi + quad * 4 + r;
                float vv[NF];
                float rm = -1e30f;
                #pragma unroll
                for (int ni = 0; ni < NF; ++ni) {
                    const float v = acc[mi][ni][r] * amv[mi * 4 + r] * bn[ni];
                    vv[ni] = v;
                    rm = fmaxf(rm, v);
                    if (grow == n0 + 16 * ni + l16)
                        aux4[(long long)b * M + grow] = v;
                }
                #pragma unroll
                for (int o = 8; o > 0; o >>= 1) rm = fmaxf(rm, __shfl_xor(rm, o));
                float rs = 0.f;
                #pragma unroll
                for (int ni = 0; ni < NF; ++ni) rs += expf(vv[ni] - rm);
                #pragma unroll
                for (int o = 8; o > 0; o >>= 1) rs += __shfl_xor(rs, o);
                if (l16 == 0) {
                    const long long o = ((long long)b * M + grow) * 4 + by;
                    aux0[o] = rm; aux1[o] = rs;
                }
            }

        // col pass: lse over this block's 128 rows, reduce across quads + waves
        #pragma unroll
        for (int ni = 0; ni < NF; ++ni) {
            float va[MI * 4];
            float cm = -1e30f;
            #pragma unroll
            for (int mi = 0; mi < MI; ++mi)
                #pragma unroll
                for (int r = 0; r < 4; ++r) {
                    const float v = acc[mi][ni][r] * amv[mi * 4 + r] * bn[ni];
                    va[mi * 4 + r] = v;
                    cm = fmaxf(cm, v);
                }
            cm = fmaxf(cm, __shfl_xor(cm, 16));
            cm = fmaxf(cm, __shfl_xor(cm, 32));
            float cs = 0.f;
            #pragma unroll
            for (int j = 0; j < MI * 4; ++j) cs += expf(va[j] - cm);
            cs += __shfl_xor(cs, 16);
            cs += __shfl_xor(cs, 32);
            if (quad == 0) {
                redm[w * NT + 16 * ni + l16] = cm;
                reds[w * NT + 16 * ni + l16] = cs;
            }
        }
        __syncthreads();
        if (tid < NT) {
            float m = -1e30f, s = 0.f;
            #pragma unroll
            for (int w4 = 0; w4 < NW; ++w4) {
                const float cm = redm[w4 * NT + tid], cs = reds[w4 * NT + tid];
                const float nm = fmaxf(m, cm);
                s = s * expf(m - nm) + cs * expf(cm - nm);
                m = nm;
            }
            const long long o = ((long long)b * N + n0 + tid) * 4 + bx;
            aux2[o] = m; aux3[o] = s;
        }
    }
}

// =====================  small kernels  =====================

__global__ __launch_bounds__(256) void convert_w_k(
    const float* Wv, const float* Wt, us* Wvh, us* Wvl, us* Wth, us* Wtl)
{
    const int i = blockIdx.x * 256 + threadIdx.x;
    split_bf(Wv[i], Wvh[i], Wvl[i]);
    split_bf(Wt[i], Wth[i], Wtl[i]);
}

__global__ __launch_bounds__(256) void mean_img_k(
    const float* __restrict__ img, float* __restrict__ mimg)
{
    const int row = blockIdx.x * 4 + (threadIdx.x >> 6);
    const int lane = threadIdx.x & 63;
    const float* p = img + (long long)row * 1024;
    float s = 0.f;
    #pragma unroll
    for (int c = 0; c < 4; ++c) {
        float4 v = *(const float4*)&p[(c * 64 + lane) * 4];
        s += v.x + v.y + v.z + v.w;
    }
    #pragma unroll
    for (int o = 32; o > 0; o >>= 1) s += __shfl_xor(s, o);
    if (lane == 0) mimg[row] = s * (1.0f / 1024.0f);
}

__global__ __launch_bounds__(256) void mean_text_s1(
    const float* __restrict__ text, float* __restrict__ part)
{
    const int b = blockIdx.x, ch = blockIdx.y, k = threadIdx.x;
    const float* p = text + ((long long)b * 512 + ch * 64) * 256 + k;
    float s = 0.f;
    for (int r = 0; r < 64; ++r) s += p[r * 256];
    part[(b * 8 + ch) * 256 + k] = s;
}
__global__ __launch_bounds__(256) void mean_text_s2(
    const float* __restrict__ part, float* __restrict__ mt)
{
    const int b = blockIdx.x, k = threadIdx.x;
    float s = 0.f;
    for (int c = 0; c < 8; ++c) s += part[(b * 8 + c) * 256 + k];
    mt[b * 256 + k] = s * (1.0f / 512.0f);
}

__global__ __launch_bounds__(256) void small_adapter_k(
    const float* __restrict__ x, const float* __restrict__ W,
    const float* __restrict__ bias, float* __restrict__ y)
{
    const int b = blockIdx.x, d = threadIdx.x;
    __shared__ float xs[256];
    xs[d] = x[b * 256 + d];
    __syncthreads();
    const float4* w = (const float4*)(W + (long long)d * 256);
    const float4* xv = (const float4*)xs;
    float s = bias[d];
    #pragma unroll 8
    for (int k = 0; k < 64; ++k) {
        const float4 a = xv[k], ww = w[k];
        s += a.x * ww.x + a.y * ww.y + a.z * ww.z + a.w * ww.w;
    }
    y[b * 256 + d] = s;
}

// ---- parallelized global loss ----

__global__ __launch_bounds__(256) void inv_norm_f32_k(
    const float* __restrict__ x, float* __restrict__ inv)
{
    const int row = blockIdx.x * 4 + (threadIdx.x >> 6);
    const int lane = threadIdx.x & 63;
    float4 v = *(const float4*)&x[(long long)row * 256 + lane * 4];
    float s = v.x * v.x + v.y * v.y + v.z * v.z + v.w * v.w;
    #pragma unroll
    for (int o = 32; o > 0; o >>= 1) s += __shfl_xor(s, o);
    if (lane == 0) inv[row] = 1.0f / fmaxf(sqrtf(s), 1e-8f);
}

__global__ __launch_bounds__(256) void g_sim_k(
    const float* __restrict__ gi, const float* __restrict__ gt,
    const float* __restrict__ invI, const float* __restrict__ invT,
    float* __restrict__ gs)
{
    const int i = blockIdx.x, t = threadIdx.x;
    const int j = t >> 2, part = t & 3;
    __shared__ float a[256];
    a[t] = gi[i * 256 + t];
    __syncthreads();
    const float* bp = gt + (long long)j * 256 + part * 64;
    const float* ap = a + part * 64;
    float s = 0.f;
    #pragma unroll 16
    for (int k = 0; k < 64; ++k) s += ap[k] * bp[k];
    s += __shfl_xor(s, 1);
    s += __shfl_xor(s, 2);
    if (part == 0) gs[i * 64 + j] = s * invI[i] * invT[j] * TAU_INV;
}

__global__ __launch_bounds__(64) void g_lse_k(
    const float* __restrict__ gs, float* __restrict__ out)
{
    const int b = blockIdx.x, lane = threadIdx.x;
    const bool is_col = b >= 64;
    const int r = is_col ? b - 64 : b;
    const float v = is_col ? gs[lane * 64 + r] : gs[r * 64 + lane];
    float m = v;
    #pragma unroll
    for (int o = 32; o > 0; o >>= 1) m = fmaxf(m, __shfl_xor(m, o));
    float s = expf(v - m);
    #pragma unroll
    for (int o = 32; o > 0; o >>= 1) s += __shfl_xor(s, o);
    if (lane == 0)
        atomicAdd(out, ((m + logf(s)) - gs[r * 64 + r]) * (0.5f / 64.0f));
}

// inv L2 norm of 256-wide single-bf16 rows
__global__ __launch_bounds__(256) void inv_norm_b16_k(
    const us* __restrict__ x, float* __restrict__ inv)
{
    const int row = blockIdx.x * 4 + (threadIdx.x >> 6);
    const int lane = threadIdx.x & 63;
    ushort4 h = *(const ushort4*)&x[(long long)row * 256 + lane * 4];
    const float x0 = bf2f(h.x), x1 = bf2f(h.y), x2 = bf2f(h.z), x3 = bf2f(h.w);
    float s = x0 * x0 + x1 * x1 + x2 * x2 + x3 * x3;
    #pragma unroll
    for (int o = 32; o > 0; o >>= 1) s += __shfl_xor(s, o);
    if (lane == 0) inv[row] = 1.0f / fmaxf(sqrtf(s), 1e-8f);
}

// ---- merge kernels ----

// merge 8 minmax partials per (b,s); grid 128 x 256
__global__ __launch_bounds__(256) void minmax_merge_k(
    const float* __restrict__ mnp, const float* __restrict__ mxp,
    float* __restrict__ mn, float* __restrict__ mx)
{
    const int idx = blockIdx.x * 256 + threadIdx.x;
    float lo = 1e30f, hi = -1e30f;
    #pragma unroll
    for (int c = 0; c < 8; ++c) {
        lo = fminf(lo, mnp[(long long)idx * 8 + c]);
        hi = fmaxf(hi, mxp[(long long)idx * 8 + c]);
    }
    mn[idx] = lo; mx[idx] = hi;
}

// merge 4 LSE partials per row/col, subtract diag; grid 128 x 256
__global__ __launch_bounds__(256) void fine_merge4_k(
    const float* __restrict__ pm, const float* __restrict__ ps,
    const float* __restrict__ diag, float* __restrict__ out)
{
    const int idx = blockIdx.x * 256 + threadIdx.x;
    float m = -1e30f, s = 0.f;
    #pragma unroll
    for (int c = 0; c < 4; ++c) {
        const float cm = pm[(long long)idx * 4 + c], cs = ps[(long long)idx * 4 + c];
        const float nm = fmaxf(m, cm);
        s = s * expf(m - nm) + cs * expf(cm - nm);
        m = nm;
    }
    const float contrib = (m + logf(s)) - diag[idx];
    __shared__ float red[256];
    red[threadIdx.x] = contrib;
    __syncthreads();
    for (int w = 128; w > 0; w >>= 1) {
        if (threadIdx.x < w) red[threadIdx.x] += red[threadIdx.x + w];
        __syncthreads();
    }
    if (threadIdx.x == 0) atomicAdd(out, red[0] * (0.5f / (64.0f * 512.0f)));
}

extern "C" void kernel_launch(void* const* d_in, const int* in_sizes, int n_in,
                              void* d_out, int out_size, void* d_ws, size_t ws_size,
                              hipStream_t stream)
{
    const float* img  = (const float*)d_in[0];
    const float* text = (const float*)d_in[1];
    const float* Wv   = (const float*)d_in[2];
    const float* bv   = (const float*)d_in[3];
    const float* Wt   = (const float*)d_in[4];
    const float* bt   = (const float*)d_in[5];
    float* out = (float*)d_out;
    char* ws = (char*)d_ws;

    us* patches = (us*)(ws + 0);              // 33,554,432 B
    us* tokens  = (us*)(ws + 33554432);       // 16,777,216 B
    us* simT    = (us*)(ws + 50331648);       // 67,108,864 B  ([b][s][p])
    us* lgve    = (us*)(ws + 117440512);      // 16,777,216 B
    char* st = ws + 134217728;
    float* mean_img  = (float*)(st + 0);
    float* mean_text = (float*)(st + 65536);
    float* mean_pat  = (float*)(st + 131072);
    float* mean_tok  = (float*)(st + 196608);
    float* g_img     = (float*)(st + 262144);
    float* g_txt     = (float*)(st + 327680);
    float* textpart  = (float*)(st + 393216);
    float* mnp       = (float*)(st + 917504);   // 1 MB
    float* mxp       = (float*)(st + 1966080);  // 1 MB
    float* mnv       = (float*)(st + 3014656);
    float* mxv       = (float*)(st + 3145728);
    float* inv_l     = (float*)(st + 3276800);
    float* inv_t     = (float*)(st + 3407872);
    us* Wvh = (us*)(st + 3538944);
    us* Wvl = (us*)(st + 3670016);
    us* Wth = (us*)(st + 3801088);
    us* Wtl = (us*)(st + 3932160);
    float* inv_gi  = (float*)(st + 4063232);
    float* inv_gt  = (float*)(st + 4063744);
    float* g_simbf = (float*)(st + 4064256);
    float* pm_row  = (float*)(st + 4194304);   // 512 KB (4 partials/row)
    float* ps_row  = (float*)(st + 4718592);   // 512 KB
    float* pm_col  = (float*)(st + 5242880);   // 512 KB
    float* ps_col  = (float*)(st + 5767168);   // 512 KB
    float* diag    = (float*)(st + 6291456);   // 128 KB

    zero_out_k<<<1, 64, 0, stream>>>(out);
    convert_w_k<<<256, 256, 0, stream>>>(Wv, Wt, Wvh, Wvl, Wth, Wtl);

    // Global path (mean commutes with linear)
    mean_img_k<<<4096, 256, 0, stream>>>(img, mean_img);
    mean_text_s1<<<dim3(64, 8), 256, 0, stream>>>(text, textpart);
    mean_text_s2<<<64, 256, 0, stream>>>(textpart, mean_text);
    small_adapter_k<<<BB, 256, 0, stream>>>(mean_img, Wv, bv, mean_pat);
    small_adapter_k<<<BB, 256, 0, stream>>>(mean_pat, Wv, bv, g_img);
    small_adapter_k<<<BB, 256, 0, stream>>>(mean_text, Wt, bt, mean_tok);
    small_adapter_k<<<BB, 256, 0, stream>>>(mean_tok, Wt, bt, g_txt);
    inv_norm_f32_k<<<16, 256, 0, stream>>>(g_img, inv_gi);
    inv_norm_f32_k<<<16, 256, 0, stream>>>(g_txt, inv_gt);
    g_sim_k<<<64, 256, 0, stream>>>(g_img, g_txt, inv_gi, inv_gt, g_simbf);
    g_lse_k<<<128, 64, 0, stream>>>(g_simbf, out);

    // G1: patches = img.Wv + bv; R16: NW=8 (512 thr) — acc 128->64 VGPR,
    // per-thread staging halves, 16 waves/CU (was 184 VGPR / 9.9% occupancy)
    mfma_gemm<OPM_F32_COL, OPM_SPL_ROW, OUT_B16, 1, 256, 0, 8, 0><<<dim3(8, 1, BB), 512, 0, stream>>>(
        img, nullptr, Wvh, Wvl, patches,
        1024, 256, 256, 1024, 256, 256,
        1048576LL, 0LL, 524288LL, bv, nullptr, nullptr, 0.f, nullptr, nullptr,
        nullptr, nullptr, nullptr, nullptr, nullptr);

    // G2: tokens = text.Wt + bt; R16: NW=8
    mfma_gemm<OPM_F32_ROW, OPM_SPL_ROW, OUT_B16, 1, 256, 0, 8, 0><<<dim3(4, 1, BB), 512, 0, stream>>>(
        text, nullptr, Wth, Wtl, tokens,
        512, 256, 256, 256, 256, 256,
        524288LL, 0LL, 262144LL, bt, nullptr, nullptr, 0.f, nullptr, nullptr,
        nullptr, nullptr, nullptr, nullptr, nullptr);

    // G4': simT = tokens . patches^T, DMA-staged, row-minmax fused.
    mfma_gemm<OPM_B16_ROW, OPM_B16_ROW, OUT_B16, 3, 128, 0, 8, 1><<<dim3(4, 8, BB), 512, 0, stream>>>(
        tokens, nullptr, patches, nullptr, simT,
        512, 1024, 256, 256, 256, 1024,
        262144LL, 524288LL, 1048576LL, nullptr, nullptr, nullptr, 0.f, nullptr, nullptr,
        mnp, mxp, nullptr, nullptr, nullptr);

    minmax_merge_k<<<128, 256, 0, stream>>>(mnp, mxp, mnv, mxv);

    // G6: lgve = w.patches; A = simT row-wise + fused weight transform,
    // B = patches col (scalar), reg-staged path.
    mfma_gemm<OPM_WGT_ROW, OPM_B16_COL, OUT_B16, 0, 128, 1, 8, 0><<<dim3(4, 2, BB), 512, 0, stream>>>(
        simT, nullptr, patches, nullptr, lgve,
        512, 256, 1024, 1024, 256, 256,
        1048576LL, 524288LL, 262144LL, nullptr, nullptr, nullptr, 0.f, mnv, mxv,
        nullptr, nullptr, nullptr, nullptr, nullptr);

    inv_norm_b16_k<<<8192, 256, 0, stream>>>(lgve, inv_l);
    inv_norm_b16_k<<<8192, 256, 0, stream>>>(tokens, inv_t);

    // G8: f_sim never materialized; DMA-staged, 4 row + 4 col LSE partials
    mfma_gemm<OPM_B16_ROW, OPM_B16_ROW, OUT_B16, 4, 128, 0, 8, 1><<<dim3(4, 4, BB), 512, 0, stream>>>(
        lgve, nullptr, tokens, nullptr, nullptr,
        512, 512, 256, 256, 256, 512,
        262144LL, 262144LL, 0LL, nullptr, inv_l, inv_t, TAU_INV, nullptr, nullptr,
        pm_row, ps_row, pm_col, ps_col, diag);

    fine_merge4_k<<<128, 256, 0, stream>>>(pm_row, ps_row, diag, out);
    fine_merge4_k<<<128, 256, 0, stream>>>(pm_col, ps_col, diag, out);
}

// Round 7
// 378.276 us; speedup vs baseline: 1.0465x; 1.0150x over previous
//
#include <hip/hip_runtime.h>
#include <math.h>

#define BB   64
#define HWP  1024
#define SS   512
#define DD   256
#define TAU_INV (1.0f/0.07f)
#define SIGMA   (1.0f/1024.0f)

typedef unsigned short us;
typedef __attribute__((ext_vector_type(8))) short short8v;
typedef __attribute__((ext_vector_type(8))) unsigned short ushort8v;
typedef __attribute__((ext_vector_type(4))) float floatx4;

__device__ __forceinline__ float bf2f(us u) {
    return __uint_as_float((unsigned)u << 16);
}
__device__ __forceinline__ us f2bf(float f) {
    unsigned u = __float_as_uint(f);
    u += 0x7FFFu + ((u >> 16) & 1u);
    return (us)(u >> 16);
}
__device__ __forceinline__ void split_bf(float v, us& h, us& l) {
    h = f2bf(v);
    l = f2bf(v - bf2f(h));
}

// R15: HBM->LDS DMA, bypasses VGPRs entirely (regalloc cannot sink it).
__device__ __forceinline__ void dma16(const us* g, us* l) {
    __builtin_amdgcn_global_load_lds(
        (const __attribute__((address_space(1))) unsigned int*)g,
        (__attribute__((address_space(3))) unsigned int*)l, 16, 0, 0);
}

__global__ void zero_out_k(float* out) { if (threadIdx.x == 0) out[0] = 0.0f; }

// =====================  MFMA GEMM  =====================
// C[m,n] = sum_k A(m,k)*B(n,k). Tile 128 x NT, BK=32, 16x16x32 bf16 MFMA.
// R15: G4'/G8 DMA pipeline (global_load_lds, dbuf, counted vmcnt) — worked.
// R16: G1/G2 NW=8 — G1 left top-5.
// R17: G6 (52us, the last reg-staged big GEMM) — its B operand was 8 scalar
//      2B col-loads/thread/k-step with regalloc-defeated prefetch (VGPR 48).
//      Fix: patchesT = patches^T once (transpose_k), then G6 runs DMA=2
//      hybrid: A = simT reg-staged (1 wide load + fused weight transform,
//      prefetched under MFMA), B = dma16 from patchesT, dbuf, counted vmcnt.
//      VMEM/thread/iter: 9 -> 2. Ordering invariant: B(t) issued before
//      A(t)-load, so the compiler's auto waitcnt for A's register use
//      transitively guarantees B(t) completion, leaving B(t+1) in flight.
enum { OPM_F32_ROW = 0, OPM_F32_COL = 1, OPM_SPL_ROW = 2, OPM_SPL_COL = 3,
       OPM_B16_COL = 4, OPM_B16_ROW = 5, OPM_WGT_COL = 6, OPM_WGT_ROW = 7 };
enum { OUT_F32 = 0, OUT_B16 = 1 };

#define LDSTRIDE 40

template<int MODE, int ROWS, int NW>
struct SRegs {
    static constexpr int RR = ROWS / 128;
    static constexpr bool ISF32 = (MODE == OPM_F32_ROW) || (MODE == OPM_F32_COL);
    ushort8v h[ISF32 ? 1 : RR][2];     // NW==8 paths use [rr][0] only (DCE'd)
    ushort8v l[(MODE == OPM_SPL_ROW) ? RR : 1][2];
    float4   f[ISF32 ? RR : 1][4];     // NW==8 F32 paths use f[0][0..1] only
};

// global -> registers (raw data, no conversion math)
template<int MODE, int ROWS, int NW>
__device__ __forceinline__ void stage_load(
    const char* p0, const char* p1, int ld, int row0, int k0, int tid,
    SRegs<MODE, ROWS, NW>& R)
{
    #pragma unroll
    for (int rr = 0; rr < ROWS / 128; ++rr) {
        if constexpr (MODE == OPM_SPL_ROW) {
            const us* ph = (const us*)p0;
            const us* pl = (const us*)p1;
            if constexpr (NW == 4) {
                const int i = rr * 128 + (tid >> 1), ko = (tid & 1) * 16;
                const long long g = (long long)(row0 + i) * ld + k0 + ko;
                R.h[rr][0] = *(const ushort8v*)&ph[g];
                R.h[rr][1] = *(const ushort8v*)&ph[g + 8];
                R.l[rr][0] = *(const ushort8v*)&pl[g];
                R.l[rr][1] = *(const ushort8v*)&pl[g + 8];
            } else {
                const int i = rr * 128 + (tid >> 2), ko = (tid & 3) * 8;
                const long long g = (long long)(row0 + i) * ld + k0 + ko;
                R.h[rr][0] = *(const ushort8v*)&ph[g];
                R.l[rr][0] = *(const ushort8v*)&pl[g];
            }
        } else if constexpr (MODE == OPM_B16_ROW || MODE == OPM_WGT_ROW) {
            const us* ph = (const us*)p0;
            if constexpr (NW == 4) {
                const int i = rr * 128 + (tid >> 1), ko = (tid & 1) * 16;
                const long long g = (long long)(row0 + i) * ld + k0 + ko;
                R.h[rr][0] = *(const ushort8v*)&ph[g];
                R.h[rr][1] = *(const ushort8v*)&ph[g + 8];
            } else {
                const int i = rr * 128 + (tid >> 2), ko = (tid & 3) * 8;
                const long long g = (long long)(row0 + i) * ld + k0 + ko;
                R.h[rr][0] = *(const ushort8v*)&ph[g];
            }
        } else if constexpr (MODE == OPM_F32_ROW) {
            const float* pf = (const float*)p0;
            if constexpr (NW == 4) {
                const int i = rr * 128 + (tid >> 1), ko = (tid & 1) * 16;
                const long long g = (long long)(row0 + i) * ld + k0 + ko;
                #pragma unroll
                for (int c = 0; c < 4; ++c)
                    R.f[rr][c] = *(const float4*)&pf[g + c * 4];
            } else {
                const int i = rr * 128 + (tid >> 2), ko = (tid & 3) * 8;
                const long long g = (long long)(row0 + i) * ld + k0 + ko;
                R.f[rr][0] = *(const float4*)&pf[g];
                R.f[rr][1] = *(const float4*)&pf[g + 4];
            }
        } else if constexpr (MODE == OPM_F32_COL) {
            const float* pf = (const float*)p0;
            if constexpr (NW == 4) {
                const int m = rr * 128 + (tid & 127), kh = (tid >> 7) * 16;
                const long long base = (long long)(k0 + kh) * ld + row0 + m;
                #pragma unroll
                for (int c = 0; c < 4; ++c) {
                    float4 v;
                    v.x = pf[base + (long long)(c * 4 + 0) * ld];
                    v.y = pf[base + (long long)(c * 4 + 1) * ld];
                    v.z = pf[base + (long long)(c * 4 + 2) * ld];
                    v.w = pf[base + (long long)(c * 4 + 3) * ld];
                    R.f[rr][c] = v;
                }
            } else {
                const int m = rr * 128 + (tid & 127), kh = (tid >> 7) * 8;
                const long long base = (long long)(k0 + kh) * ld + row0 + m;
                #pragma unroll
                for (int c = 0; c < 2; ++c) {
                    float4 v;
                    v.x = pf[base + (long long)(c * 4 + 0) * ld];
                    v.y = pf[base + (long long)(c * 4 + 1) * ld];
                    v.z = pf[base + (long long)(c * 4 + 2) * ld];
                    v.w = pf[base + (long long)(c * 4 + 3) * ld];
                    R.f[rr][c] = v;
                }
            }
        } else if constexpr (MODE == OPM_B16_COL) {
            const us* ph = (const us*)p0;
            if constexpr (NW == 4) {
                const int m = rr * 128 + (tid & 127), kh = (tid >> 7) * 16;
                const long long base = (long long)(k0 + kh) * ld + row0 + m;
                #pragma unroll
                for (int kk = 0; kk < 8; ++kk) {
                    R.h[rr][0][kk] = ph[base + (long long)kk * ld];
                    R.h[rr][1][kk] = ph[base + (long long)(kk + 8) * ld];
                }
            } else {
                const int m = rr * 128 + (tid & 127), kh = (tid >> 7) * 8;
                const long long base = (long long)(k0 + kh) * ld + row0 + m;
                #pragma unroll
                for (int kk = 0; kk < 8; ++kk)
                    R.h[rr][0][kk] = ph[base + (long long)kk * ld];
            }
        }
    }
}

// registers -> LDS (conversion / weight math happens here)
template<int MODE, int ROWS, int NW>
__device__ __forceinline__ void stage_store(
    const SRegs<MODE, ROWS, NW>& R, us* ldsH, us* ldsL, int tid, float nlo, float inv)
{
    #pragma unroll
    for (int rr = 0; rr < ROWS / 128; ++rr) {
        if constexpr (MODE == OPM_SPL_ROW) {
            if constexpr (NW == 4) {
                const int i = rr * 128 + (tid >> 1), ko = (tid & 1) * 16;
                *(ushort8v*)&ldsH[i * LDSTRIDE + ko]     = R.h[rr][0];
                *(ushort8v*)&ldsH[i * LDSTRIDE + ko + 8] = R.h[rr][1];
                *(ushort8v*)&ldsL[i * LDSTRIDE + ko]     = R.l[rr][0];
                *(ushort8v*)&ldsL[i * LDSTRIDE + ko + 8] = R.l[rr][1];
            } else {
                const int i = rr * 128 + (tid >> 2), ko = (tid & 3) * 8;
                *(ushort8v*)&ldsH[i * LDSTRIDE + ko] = R.h[rr][0];
                *(ushort8v*)&ldsL[i * LDSTRIDE + ko] = R.l[rr][0];
            }
        } else if constexpr (MODE == OPM_B16_ROW) {
            if constexpr (NW == 4) {
                const int i = rr * 128 + (tid >> 1), ko = (tid & 1) * 16;
                *(ushort8v*)&ldsH[i * LDSTRIDE + ko]     = R.h[rr][0];
                *(ushort8v*)&ldsH[i * LDSTRIDE + ko + 8] = R.h[rr][1];
            } else {
                const int i = rr * 128 + (tid >> 2), ko = (tid & 3) * 8;
                *(ushort8v*)&ldsH[i * LDSTRIDE + ko] = R.h[rr][0];
            }
        } else if constexpr (MODE == OPM_WGT_ROW) {
            const int i = tid >> 2, ko = (tid & 3) * 8;
            us v[8];
            #pragma unroll
            for (int j = 0; j < 8; ++j) {
                const float w0 = fmaf(bf2f(R.h[0][0][j]), inv, nlo);
                v[j] = (w0 < SIGMA) ? (us)0 : f2bf(w0);
            }
            *(ushort8v*)&ldsH[i * LDSTRIDE + ko] = *(const ushort8v*)&v[0];
        } else if constexpr (MODE == OPM_F32_ROW) {
            if constexpr (NW == 4) {
                const int i = rr * 128 + (tid >> 1), ko = (tid & 1) * 16;
                us h16[16], l16a[16];
                #pragma unroll
                for (int c = 0; c < 4; ++c) {
                    float4 v = R.f[rr][c];
                    split_bf(v.x, h16[c*4+0], l16a[c*4+0]);
                    split_bf(v.y, h16[c*4+1], l16a[c*4+1]);
                    split_bf(v.z, h16[c*4+2], l16a[c*4+2]);
                    split_bf(v.w, h16[c*4+3], l16a[c*4+3]);
                }
                *(ushort8v*)&ldsH[i * LDSTRIDE + ko]     = *(const ushort8v*)&h16[0];
                *(ushort8v*)&ldsH[i * LDSTRIDE + ko + 8] = *(const ushort8v*)&h16[8];
                *(ushort8v*)&ldsL[i * LDSTRIDE + ko]     = *(const ushort8v*)&l16a[0];
                *(ushort8v*)&ldsL[i * LDSTRIDE + ko + 8] = *(const ushort8v*)&l16a[8];
            } else {
                const int i = rr * 128 + (tid >> 2), ko = (tid & 3) * 8;
                us h8[8], l8[8];
                #pragma unroll
                for (int c = 0; c < 2; ++c) {
                    float4 v = R.f[rr][c];
                    split_bf(v.x, h8[c*4+0], l8[c*4+0]);
                    split_bf(v.y, h8[c*4+1], l8[c*4+1]);
                    split_bf(v.z, h8[c*4+2], l8[c*4+2]);
                    split_bf(v.w, h8[c*4+3], l8[c*4+3]);
                }
                *(ushort8v*)&ldsH[i * LDSTRIDE + ko] = *(const ushort8v*)&h8[0];
                *(ushort8v*)&ldsL[i * LDSTRIDE + ko] = *(const ushort8v*)&l8[0];
            }
        } else if constexpr (MODE == OPM_F32_COL) {
            if constexpr (NW == 4) {
                const int m = rr * 128 + (tid & 127), kh = (tid >> 7) * 16;
                us vh[16], vl[16];
                #pragma unroll
                for (int c = 0; c < 4; ++c) {
                    float4 v = R.f[rr][c];
                    split_bf(v.x, vh[c*4+0], vl[c*4+0]);
                    split_bf(v.y, vh[c*4+1], vl[c*4+1]);
                    split_bf(v.z, vh[c*4+2], vl[c*4+2]);
                    split_bf(v.w, vh[c*4+3], vl[c*4+3]);
                }
                *(ushort8v*)&ldsH[m * LDSTRIDE + kh]     = *(const ushort8v*)&vh[0];
                *(ushort8v*)&ldsH[m * LDSTRIDE + kh + 8] = *(const ushort8v*)&vh[8];
                *(ushort8v*)&ldsL[m * LDSTRIDE + kh]     = *(const ushort8v*)&vl[0];
                *(ushort8v*)&ldsL[m * LDSTRIDE + kh + 8] = *(const ushort8v*)&vl[8];
            } else {
                const int m = rr * 128 + (tid & 127), kh = (tid >> 7) * 8;
                us vh[8], vl[8];
                #pragma unroll
                for (int c = 0; c < 2; ++c) {
                    float4 v = R.f[rr][c];
                    split_bf(v.x, vh[c*4+0], vl[c*4+0]);
                    split_bf(v.y, vh[c*4+1], vl[c*4+1]);
                    split_bf(v.z, vh[c*4+2], vl[c*4+2]);
                    split_bf(v.w, vh[c*4+3], vl[c*4+3]);
                }
                *(ushort8v*)&ldsH[m * LDSTRIDE + kh] = *(const ushort8v*)&vh[0];
                *(ushort8v*)&ldsL[m * LDSTRIDE + kh] = *(const ushort8v*)&vl[0];
            }
        } else if constexpr (MODE == OPM_B16_COL) {
            if constexpr (NW == 4) {
                const int m = rr * 128 + (tid & 127), kh = (tid >> 7) * 16;
                us v[16];
                #pragma unroll
                for (int kk = 0; kk < 16; ++kk)
                    v[kk] = (kk < 8) ? R.h[rr][0][kk & 7] : R.h[rr][1][kk & 7];
                *(ushort8v*)&ldsH[m * LDSTRIDE + kh]     = *(const ushort8v*)&v[0];
                *(ushort8v*)&ldsH[m * LDSTRIDE + kh + 8] = *(const ushort8v*)&v[8];
            } else {
                const int m = rr * 128 + (tid & 127), kh = (tid >> 7) * 8;
                *(ushort8v*)&ldsH[m * LDSTRIDE + kh] = R.h[rr][0];
            }
        }
    }
}

template<int AMODE, int BMODE, int OMODE, int EPI, int NT, int PREF, int NW, int DMA>
__global__ __launch_bounds__(NW * 64) void mfma_gemm(
    const void* A0, const void* A1, const void* B0, const void* B1, void* C0,
    int M, int N, int K, int lda, int ldb, int ldc,
    long long sA, long long sB, long long sC,
    const float* __restrict__ bias, const float* __restrict__ invm,
    const float* __restrict__ invn, float scale,
    const float* __restrict__ wlo, const float* __restrict__ whi,
    float* __restrict__ aux0, float* __restrict__ aux1,
    float* __restrict__ aux2, float* __restrict__ aux3, float* __restrict__ aux4)
{
    constexpr bool ASPL = (AMODE <= OPM_SPL_COL);
    constexpr bool BSPL = (BMODE <= OPM_SPL_COL);
    constexpr int NF = NT / 16;
    constexpr int MI = 8 / NW;         // 16-row frags per wave (2 @NW4, 1 @NW8)
    constexpr int RPW = 128 / NW;      // rows per wave
    __shared__ __align__(16) us Ah[(DMA == 1) ? 8 : 128 * LDSTRIDE];
    __shared__ __align__(16) us Al[(!DMA && ASPL) ? 128 * LDSTRIDE : 8];
    __shared__ __align__(16) us Bh[DMA ? 8 : NT * LDSTRIDE];
    __shared__ __align__(16) us Bl[(!DMA && BSPL) ? NT * LDSTRIDE : 8];
    __shared__ __align__(16) us AhD[(DMA == 1) ? 2 * 128 * 32 : 8]; // linear dbuf
    __shared__ __align__(16) us BhD[DMA ? 2 * NT * 32 : 8];
    __shared__ float redm[(EPI == 4) ? NW * NT : 1];
    __shared__ float reds[(EPI == 4) ? NW * NT : 1];

    const int tid = threadIdx.x;
    const int w = tid >> 6, lane = tid & 63;
    const int quad = lane >> 4, l16 = lane & 15;

    // XCD-chunked bijective swizzle (nwg % 8 == 0 for all grids here).
    int bx = blockIdx.x, by = blockIdx.y, bz = blockIdx.z;
    {
        const int nbx = gridDim.x, nby = gridDim.y, nbz = gridDim.z;
        const int nwg = nbx * nby * nbz;
        if ((nwg & 7) == 0) {
            const int hw = bx + nbx * (by + nby * bz);
            const int cpx = nwg >> 3;
            int wk = (hw & 7) * cpx + (hw >> 3);
            bx = wk % nbx; wk /= nbx;
            by = wk % nby; bz = wk / nby;
        }
    }

    const int m0 = bx * 128, n0 = by * NT;
    const int b = bz;

    const char* Ab0 = (const char*)A0 + (long long)b * sA;
    const char* Ab1 = A1 ? (const char*)A1 + (long long)b * sA : nullptr;
    const char* Bb0 = (const char*)B0 + (long long)b * sB;
    const char* Bb1 = B1 ? (const char*)B1 + (long long)b * sB : nullptr;

    floatx4 acc[MI][NF];
    #pragma unroll
    for (int mi = 0; mi < MI; ++mi)
        #pragma unroll
        for (int ni = 0; ni < NF; ++ni)
            acc[mi][ni] = (floatx4){0.f, 0.f, 0.f, 0.f};

    if constexpr (DMA == 1) {
        // ================= R15a: DMA-staged pipeline (ROW/ROW only) =========
        const us* Abu = (const us*)Ab0;
        const us* Bbu = (const us*)Bb0;
        const int drow = 16 * w + (lane >> 2);
        const int dcol = (lane & 3) * 8;
        const us* aS = Abu + (long long)(m0 + drow) * lda + dcol;
        const us* bS = Bbu + (long long)(n0 + drow) * ldb + dcol;
        us* aD = &AhD[0] + 512 * w;
        us* bD = &BhD[0] + 512 * w;
        const int NTL = K >> 5;

        dma16(aS,      aD);
        dma16(bS,      bD);
        dma16(aS + 32, aD + 128 * 32);
        dma16(bS + 32, bD + NT * 32);

        int cur = 0;
        for (int t = 0; t < NTL; ++t) {
            if (t + 1 == NTL) asm volatile("s_waitcnt vmcnt(0)" ::: "memory");
            else              asm volatile("s_waitcnt vmcnt(2)" ::: "memory");
            __builtin_amdgcn_s_barrier();
            asm volatile("" ::: "memory");

            {
                const us* Ac = &AhD[cur * 128 * 32];
                const us* Bc = &BhD[cur * NT * 32];
                short8v ah = *(const short8v*)&Ac[(16 * w + l16) * 32 + quad * 8];
                #pragma unroll
                for (int ni = 0; ni < NF; ++ni) {
                    short8v bh = *(const short8v*)&Bc[(16 * ni + l16) * 32 + quad * 8];
                    acc[0][ni] = __builtin_amdgcn_mfma_f32_16x16x32_bf16(ah, bh, acc[0][ni], 0, 0, 0);
                }
            }

            asm volatile("" ::: "memory");
            __builtin_amdgcn_s_barrier();
            if (t + 2 < NTL) {
                const long long off = (long long)(t + 2) * 32;
                dma16(aS + off, aD + cur * 128 * 32);
                dma16(bS + off, bD + cur * NT * 32);
            }
            cur ^= 1;
        }
    } else if constexpr (DMA == 2) {
        // ===== R17: hybrid — A reg-staged (WGT transform), B DMA-staged =====
        // Per iter per thread: 1 wide A load + 1 dma16 (was 1 + 8 scalar).
        // Issue-order invariant: B(t) always older than A(t)'s load, so the
        // compiler's auto vmcnt for A's register use guarantees B(t) done
        // while B(t+1) stays in flight. vmcnt(1) below is a safety belt.
        const us* Abu = (const us*)Ab0;   // simT
        const us* Bbu = (const us*)Bb0;   // patchesT
        const float* wloA = wlo + (long long)b * M;
        const float* whiA = whi + (long long)b * M;
        const int ai = tid >> 2, ako = (tid & 3) * 8;
        const float lo = wloA[m0 + ai];
        const float invA = 1.0f / (whiA[m0 + ai] - lo + 1e-8f);
        const float nloA = -lo * invA;

        const int rB = 16 * w + (lane >> 2);
        const us* bS = Bbu + (long long)(n0 + rB) * ldb + (lane & 3) * 8;
        us* bD = &BhD[0] + 512 * w;
        const long long aRow = (long long)(m0 + ai) * lda + ako;
        const int NTL = K >> 5;

        dma16(bS, bD);                                   // B(0) first
        ushort8v ra = *(const ushort8v*)&Abu[aRow];      // A(0)
        dma16(bS + 32, bD + 4096);                       // B(1)

        int cur = 0;
        for (int t = 0; t < NTL; ++t) {
            us v[8];
            #pragma unroll
            for (int j = 0; j < 8; ++j) {
                const float w0 = fmaf(bf2f(ra[j]), invA, nloA);
                v[j] = (w0 < SIGMA) ? (us)0 : f2bf(w0);
            }
            *(ushort8v*)&Ah[ai * LDSTRIDE + ako] = *(const ushort8v*)&v[0];
            asm volatile("s_waitcnt vmcnt(1) lgkmcnt(0)" ::: "memory");
            __builtin_amdgcn_s_barrier();

            // prefetch next A under the MFMA phase
            if (t + 1 < NTL)
                ra = *(const ushort8v*)&Abu[aRow + (long long)(t + 1) * 32];

            {
                const us* Bc = &BhD[cur * 4096];
                short8v ah = *(const short8v*)&Ah[(16 * w + l16) * LDSTRIDE + quad * 8];
                #pragma unroll
                for (int ni = 0; ni < NF; ++ni) {
                    short8v bh = *(const short8v*)&Bc[(16 * ni + l16) * 32 + quad * 8];
                    acc[0][ni] = __builtin_amdgcn_mfma_f32_16x16x32_bf16(ah, bh, acc[0][ni], 0, 0, 0);
                }
            }
            asm volatile("" ::: "memory");
            __builtin_amdgcn_s_barrier();
            if (t + 2 < NTL)
                dma16(bS + (long long)(t + 2) * 32, bD + cur * 4096);
            cur ^= 1;
        }
    } else {
        // ================= reg-staged path (G1/G2) =========================
        float nloA = 0.f, invA = 0.f;
        if constexpr (AMODE == OPM_WGT_ROW) {
            const float* wloA = wlo + (long long)b * M;
            const float* whiA = whi + (long long)b * M;
            const int row = m0 + (tid >> 2);
            const float lo = wloA[row];
            invA = 1.0f / (whiA[row] - lo + 1e-8f);
            nloA = -lo * invA;
        }

        SRegs<AMODE, 128, NW> RA0, RA1;
        SRegs<BMODE, NT, NW>  RB0, RB1;
        if constexpr (PREF) {
            stage_load<AMODE, 128, NW>(Ab0, Ab1, lda, m0, 0, tid, RA0);
            stage_load<BMODE, NT, NW>(Bb0, Bb1, ldb, n0, 0, tid, RB0);
            stage_load<AMODE, 128, NW>(Ab0, Ab1, lda, m0, 32, tid, RA1);
            stage_load<BMODE, NT, NW>(Bb0, Bb1, ldb, n0, 32, tid, RB1);
        }

        auto do_mfma = [&]() {
            short8v ah[MI], al[MI];
            #pragma unroll
            for (int mi = 0; mi < MI; ++mi) {
                const int r = (RPW * w + 16 * mi + l16) * LDSTRIDE + quad * 8;
                ah[mi] = *(const short8v*)&Ah[r];
                if constexpr (ASPL) al[mi] = *(const short8v*)&Al[r];
            }
            #pragma unroll
            for (int ni = 0; ni < NF; ++ni) {
                const int rB = (16 * ni + l16) * LDSTRIDE + quad * 8;
                short8v bh = *(const short8v*)&Bh[rB];
                #pragma unroll
                for (int mi = 0; mi < MI; ++mi)
                    acc[mi][ni] = __builtin_amdgcn_mfma_f32_16x16x32_bf16(ah[mi], bh, acc[mi][ni], 0, 0, 0);
                if constexpr (BSPL) {
                    short8v bl = *(const short8v*)&Bl[rB];
                    #pragma unroll
                    for (int mi = 0; mi < MI; ++mi)
                        acc[mi][ni] = __builtin_amdgcn_mfma_f32_16x16x32_bf16(ah[mi], bl, acc[mi][ni], 0, 0, 0);
                }
                if constexpr (ASPL) {
                    #pragma unroll
                    for (int mi = 0; mi < MI; ++mi)
                        acc[mi][ni] = __builtin_amdgcn_mfma_f32_16x16x32_bf16(al[mi], bh, acc[mi][ni], 0, 0, 0);
                }
            }
        };

#define GEMM_SUBSTEP(RAx, RBx, KCUR, KNEXT)                                    \
    do {                                                                       \
        if constexpr (!PREF) {                                                 \
            stage_load<AMODE, 128, NW>(Ab0, Ab1, lda, m0, (KCUR), tid, RAx);   \
            stage_load<BMODE, NT, NW>(Bb0, Bb1, ldb, n0, (KCUR), tid, RBx);    \
        }                                                                      \
        stage_store<AMODE, 128, NW>(RAx, Ah, Al, tid, nloA, invA);             \
        stage_store<BMODE, NT, NW>(RBx, Bh, Bl, tid, 0.f, 0.f);                \
        if constexpr (PREF) {                                                  \
            asm volatile("s_waitcnt lgkmcnt(0)" ::: "memory");                 \
            __builtin_amdgcn_s_barrier();                                      \
            if ((KNEXT) < K) {                                                 \
                stage_load<AMODE, 128, NW>(Ab0, Ab1, lda, m0, (KNEXT), tid, RAx); \
                stage_load<BMODE, NT, NW>(Bb0, Bb1, ldb, n0, (KNEXT), tid, RBx);  \
            }                                                                  \
        } else {                                                               \
            __syncthreads();                                                   \
        }                                                                      \
        do_mfma();                                                             \
        if constexpr (PREF) {                                                  \
            asm volatile("s_waitcnt lgkmcnt(0)" ::: "memory");                 \
            __builtin_amdgcn_s_barrier();                                      \
        } else {                                                               \
            __syncthreads();                                                   \
        }                                                                      \
    } while (0)

        for (int k0 = 0; k0 < K; k0 += 64) {
            GEMM_SUBSTEP(RA0, RB0, k0, k0 + 64);
            GEMM_SUBSTEP(RA1, RB1, k0 + 32, k0 + 96);
        }
#undef GEMM_SUBSTEP
    }

    if constexpr (EPI != 4) {
        char* Cb0 = (char*)C0 + (long long)b * sC;
        #pragma unroll
        for (int mi = 0; mi < MI; ++mi)
            #pragma unroll
            for (int ni = 0; ni < NF; ++ni)
                #pragma unroll
                for (int r = 0; r < 4; ++r) {
                    const int row = m0 + RPW * w + 16 * mi + quad * 4 + r;
                    const int col = n0 + 16 * ni + l16;
                    float v = acc[mi][ni][r];
                    if constexpr (EPI == 1) v += bias[col];
                    const long long idx = (long long)row * ldc + col;
                    if constexpr (OMODE == OUT_F32) ((float*)Cb0)[idx] = v;
                    else                            ((us*)Cb0)[idx] = f2bf(v);
                }
    }

    if constexpr (EPI == 3) {
        // R15b: ROW min/max of bf16-rounded stored values (C is simT[s][p]).
        #pragma unroll
        for (int r = 0; r < 4; ++r) {
            const int grow = m0 + RPW * w + quad * 4 + r;
            float lo = 1e30f, hi = -1e30f;
            #pragma unroll
            for (int ni = 0; ni < NF; ++ni) {
                const float vr = bf2f(f2bf(acc[0][ni][r]));
                lo = fminf(lo, vr); hi = fmaxf(hi, vr);
            }
            lo = fminf(lo, __shfl_xor(lo, 1)); hi = fmaxf(hi, __shfl_xor(hi, 1));
            lo = fminf(lo, __shfl_xor(lo, 2)); hi = fmaxf(hi, __shfl_xor(hi, 2));
            lo = fminf(lo, __shfl_xor(lo, 4)); hi = fmaxf(hi, __shfl_xor(hi, 4));
            lo = fminf(lo, __shfl_xor(lo, 8)); hi = fmaxf(hi, __shfl_xor(hi, 8));
            if (l16 == 0) {
                const long long o = ((long long)b * M + grow) * 8 + by;
                aux0[o] = lo; aux1[o] = hi;
            }
        }
    }

    if constexpr (EPI == 4) {
        // f_sim never stored: emit row/col LSE partials + diagonal.
        float bn[NF];
        #pragma unroll
        for (int ni = 0; ni < NF; ++ni)
            bn[ni] = invn[(long long)b * N + n0 + 16 * ni + l16] * scale;
        float amv[MI * 4];
        #pragma unroll
        for (int mi = 0; mi < MI; ++mi)
            #pragma unroll
            for (int r = 0; r < 4; ++r)
                amv[mi * 4 + r] = invm[(long long)b * M + m0 + RPW * w + 16 * mi + quad * 4 + r];

        // row pass: lse over this block's NT cols, reduce across l16
        #pragma unroll
        for (int mi = 0; mi < MI; ++mi)
            #pragma unroll
            for (int r = 0; r < 4; ++r) {
                const int grow = m0 + RPW * w + 16 * mi + quad * 4 + r;
                float vv[NF];
                float rm = -1e30f;
                #pragma unroll
                for (int ni = 0; ni < NF; ++ni) {
                    const float v = acc[mi][ni][r] * amv[mi * 4 + r] * bn[ni];
                    vv[ni] = v;
                    rm = fmaxf(rm, v);
                    if (grow == n0 + 16 * ni + l16)
                        aux4[(long long)b * M + grow] = v;
                }
                #pragma unroll
                for (int o = 8; o > 0; o >>= 1) rm = fmaxf(rm, __shfl_xor(rm, o));
                float rs = 0.f;
                #pragma unroll
                for (int ni = 0; ni < NF; ++ni) rs += expf(vv[ni] - rm);
                #pragma unroll
                for (int o = 8; o > 0; o >>= 1) rs += __shfl_xor(rs, o);
                if (l16 == 0) {
                    const long long o = ((long long)b * M + grow) * 4 + by;
                    aux0[o] = rm; aux1[o] = rs;
                }
            }

        // col pass: lse over this block's 128 rows, reduce across quads + waves
        #pragma unroll
        for (int ni = 0; ni < NF; ++ni) {
            float va[MI * 4];
            float cm = -1e30f;
            #pragma unroll
            for (int mi = 0; mi < MI; ++mi)
                #pragma unroll
                for (int r = 0; r < 4; ++r) {
                    const float v = acc[mi][ni][r] * amv[mi * 4 + r] * bn[ni];
                    va[mi * 4 + r] = v;
                    cm = fmaxf(cm, v);
                }
            cm = fmaxf(cm, __shfl_xor(cm, 16));
            cm = fmaxf(cm, __shfl_xor(cm, 32));
            float cs = 0.f;
            #pragma unroll
            for (int j = 0; j < MI * 4; ++j) cs += expf(va[j] - cm);
            cs += __shfl_xor(cs, 16);
            cs += __shfl_xor(cs, 32);
            if (quad == 0) {
                redm[w * NT + 16 * ni + l16] = cm;
                reds[w * NT + 16 * ni + l16] = cs;
            }
        }
        __syncthreads();
        if (tid < NT) {
            float m = -1e30f, s = 0.f;
            #pragma unroll
            for (int w4 = 0; w4 < NW; ++w4) {
                const float cm = redm[w4 * NT + tid], cs = reds[w4 * NT + tid];
                const float nm = fmaxf(m, cm);
                s = s * expf(m - nm) + cs * expf(cm - nm);
                m = nm;
            }
            const long long o = ((long long)b * N + n0 + tid) * 4 + bx;
            aux2[o] = m; aux3[o] = s;
        }
    }
}

// =====================  small kernels  =====================

// R17: patchesT[b][d][p] = patches[b][p][d]; 64x64 LDS tiles.
__global__ __launch_bounds__(256) void transpose_k(
    const us* __restrict__ src, us* __restrict__ dst)
{
    __shared__ us t[64][66];
    const int b = blockIdx.z;
    const int p0 = blockIdx.x * 64, d0 = blockIdx.y * 64;
    const us* s = src + (long long)b * 262144;
    us* d = dst + (long long)b * 262144;
    const int r = threadIdx.x >> 3, c8 = (threadIdx.x & 7) * 8;
    #pragma unroll
    for (int h = 0; h < 64; h += 32)
        *(ushort8v*)&t[r + h][c8] =
            *(const ushort8v*)&s[(long long)(p0 + r + h) * 256 + d0 + c8];
    __syncthreads();
    #pragma unroll
    for (int h = 0; h < 64; h += 32) {
        us v[8];
        #pragma unroll
        for (int j = 0; j < 8; ++j) v[j] = t[c8 + j][r + h];
        *(ushort8v*)&d[(long long)(d0 + r + h) * 1024 + p0 + c8] =
            *(const ushort8v*)&v[0];
    }
}

__global__ __launch_bounds__(256) void convert_w_k(
    const float* Wv, const float* Wt, us* Wvh, us* Wvl, us* Wth, us* Wtl)
{
    const int i = blockIdx.x * 256 + threadIdx.x;
    split_bf(Wv[i], Wvh[i], Wvl[i]);
    split_bf(Wt[i], Wth[i], Wtl[i]);
}

__global__ __launch_bounds__(256) void mean_img_k(
    const float* __restrict__ img, float* __restrict__ mimg)
{
    const int row = blockIdx.x * 4 + (threadIdx.x >> 6);
    const int lane = threadIdx.x & 63;
    const float* p = img + (long long)row * 1024;
    float s = 0.f;
    #pragma unroll
    for (int c = 0; c < 4; ++c) {
        float4 v = *(const float4*)&p[(c * 64 + lane) * 4];
        s += v.x + v.y + v.z + v.w;
    }
    #pragma unroll
    for (int o = 32; o > 0; o >>= 1) s += __shfl_xor(s, o);
    if (lane == 0) mimg[row] = s * (1.0f / 1024.0f);
}

__global__ __launch_bounds__(256) void mean_text_s1(
    const float* __restrict__ text, float* __restrict__ part)
{
    const int b = blockIdx.x, ch = blockIdx.y, k = threadIdx.x;
    const float* p = text + ((long long)b * 512 + ch * 64) * 256 + k;
    float s = 0.f;
    for (int r = 0; r < 64; ++r) s += p[r * 256];
    part[(b * 8 + ch) * 256 + k] = s;
}
__global__ __launch_bounds__(256) void mean_text_s2(
    const float* __restrict__ part, float* __restrict__ mt)
{
    const int b = blockIdx.x, k = threadIdx.x;
    float s = 0.f;
    for (int c = 0; c < 8; ++c) s += part[(b * 8 + c) * 256 + k];
    mt[b * 256 + k] = s * (1.0f / 512.0f);
}

__global__ __launch_bounds__(256) void small_adapter_k(
    const float* __restrict__ x, const float* __restrict__ W,
    const float* __restrict__ bias, float* __restrict__ y)
{
    const int b = blockIdx.x, d = threadIdx.x;
    __shared__ float xs[256];
    xs[d] = x[b * 256 + d];
    __syncthreads();
    const float4* w = (const float4*)(W + (long long)d * 256);
    const float4* xv = (const float4*)xs;
    float s = bias[d];
    #pragma unroll 8
    for (int k = 0; k < 64; ++k) {
        const float4 a = xv[k], ww = w[k];
        s += a.x * ww.x + a.y * ww.y + a.z * ww.z + a.w * ww.w;
    }
    y[b * 256 + d] = s;
}

// ---- parallelized global loss ----

__global__ __launch_bounds__(256) void inv_norm_f32_k(
    const float* __restrict__ x, float* __restrict__ inv)
{
    const int row = blockIdx.x * 4 + (threadIdx.x >> 6);
    const int lane = threadIdx.x & 63;
    float4 v = *(const float4*)&x[(long long)row * 256 + lane * 4];
    float s = v.x * v.x + v.y * v.y + v.z * v.z + v.w * v.w;
    #pragma unroll
    for (int o = 32; o > 0; o >>= 1) s += __shfl_xor(s, o);
    if (lane == 0) inv[row] = 1.0f / fmaxf(sqrtf(s), 1e-8f);
}

__global__ __launch_bounds__(256) void g_sim_k(
    const float* __restrict__ gi, const float* __restrict__ gt,
    const float* __restrict__ invI, const float* __restrict__ invT,
    float* __restrict__ gs)
{
    const int i = blockIdx.x, t = threadIdx.x;
    const int j = t >> 2, part = t & 3;
    __shared__ float a[256];
    a[t] = gi[i * 256 + t];
    __syncthreads();
    const float* bp = gt + (long long)j * 256 + part * 64;
    const float* ap = a + part * 64;
    float s = 0.f;
    #pragma unroll 16
    for (int k = 0; k < 64; ++k) s += ap[k] * bp[k];
    s += __shfl_xor(s, 1);
    s += __shfl_xor(s, 2);
    if (part == 0) gs[i * 64 + j] = s * invI[i] * invT[j] * TAU_INV;
}

__global__ __launch_bounds__(64) void g_lse_k(
    const float* __restrict__ gs, float* __restrict__ out)
{
    const int b = blockIdx.x, lane = threadIdx.x;
    const bool is_col = b >= 64;
    const int r = is_col ? b - 64 : b;
    const float v = is_col ? gs[lane * 64 + r] : gs[r * 64 + lane];
    float m = v;
    #pragma unroll
    for (int o = 32; o > 0; o >>= 1) m = fmaxf(m, __shfl_xor(m, o));
    float s = expf(v - m);
    #pragma unroll
    for (int o = 32; o > 0; o >>= 1) s += __shfl_xor(s, o);
    if (lane == 0)
        atomicAdd(out, ((m + logf(s)) - gs[r * 64 + r]) * (0.5f / 64.0f));
}

// inv L2 norm of 256-wide single-bf16 rows
__global__ __launch_bounds__(256) void inv_norm_b16_k(
    const us* __restrict__ x, float* __restrict__ inv)
{
    const int row = blockIdx.x * 4 + (threadIdx.x >> 6);
    const int lane = threadIdx.x & 63;
    ushort4 h = *(const ushort4*)&x[(long long)row * 256 + lane * 4];
    const float x0 = bf2f(h.x), x1 = bf2f(h.y), x2 = bf2f(h.z), x3 = bf2f(h.w);
    float s = x0 * x0 + x1 * x1 + x2 * x2 + x3 * x3;
    #pragma unroll
    for (int o = 32; o > 0; o >>= 1) s += __shfl_xor(s, o);
    if (lane == 0) inv[row] = 1.0f / fmaxf(sqrtf(s), 1e-8f);
}

// ---- merge kernels ----

__global__ __launch_bounds__(256) void minmax_merge_k(
    const float* __restrict__ mnp, const float* __restrict__ mxp,
    float* __restrict__ mn, float* __restrict__ mx)
{
    const int idx = blockIdx.x * 256 + threadIdx.x;
    float lo = 1e30f, hi = -1e30f;
    #pragma unroll
    for (int c = 0; c < 8; ++c) {
        lo = fminf(lo, mnp[(long long)idx * 8 + c]);
        hi = fmaxf(hi, mxp[(long long)idx * 8 + c]);
    }
    mn[idx] = lo; mx[idx] = hi;
}

__global__ __launch_bounds__(256) void fine_merge4_k(
    const float* __restrict__ pm, const float* __restrict__ ps,
    const float* __restrict__ diag, float* __restrict__ out)
{
    const int idx = blockIdx.x * 256 + threadIdx.x;
    float m = -1e30f, s = 0.f;
    #pragma unroll
    for (int c = 0; c < 4; ++c) {
        const float cm = pm[(long long)idx * 4 + c], cs = ps[(long long)idx * 4 + c];
        const float nm = fmaxf(m, cm);
        s = s * expf(m - nm) + cs * expf(cm - nm);
        m = nm;
    }
    const float contrib = (m + logf(s)) - diag[idx];
    __shared__ float red[256];
    red[threadIdx.x] = contrib;
    __syncthreads();
    for (int w = 128; w > 0; w >>= 1) {
        if (threadIdx.x < w) red[threadIdx.x] += red[threadIdx.x + w];
        __syncthreads();
    }
    if (threadIdx.x == 0) atomicAdd(out, red[0] * (0.5f / (64.0f * 512.0f)));
}

extern "C" void kernel_launch(void* const* d_in, const int* in_sizes, int n_in,
                              void* d_out, int out_size, void* d_ws, size_t ws_size,
                              hipStream_t stream)
{
    const float* img  = (const float*)d_in[0];
    const float* text = (const float*)d_in[1];
    const float* Wv   = (const float*)d_in[2];
    const float* bv   = (const float*)d_in[3];
    const float* Wt   = (const float*)d_in[4];
    const float* bt   = (const float*)d_in[5];
    float* out = (float*)d_out;
    char* ws = (char*)d_ws;

    us* patches = (us*)(ws + 0);              // 33,554,432 B
    us* tokens  = (us*)(ws + 33554432);       // 16,777,216 B
    us* simT    = (us*)(ws + 50331648);       // 67,108,864 B  ([b][s][p])
    us* lgve    = (us*)(ws + 117440512);      // 16,777,216 B
    char* st = ws + 134217728;
    float* mean_img  = (float*)(st + 0);
    float* mean_text = (float*)(st + 65536);
    float* mean_pat  = (float*)(st + 131072);
    float* mean_tok  = (float*)(st + 196608);
    float* g_img     = (float*)(st + 262144);
    float* g_txt     = (float*)(st + 327680);
    float* textpart  = (float*)(st + 393216);
    float* mnp       = (float*)(st + 917504);   // 1 MB
    float* mxp       = (float*)(st + 1966080);  // 1 MB
    float* mnv       = (float*)(st + 3014656);
    float* mxv       = (float*)(st + 3145728);
    float* inv_l     = (float*)(st + 3276800);
    float* inv_t     = (float*)(st + 3407872);
    us* Wvh = (us*)(st + 3538944);
    us* Wvl = (us*)(st + 3670016);
    us* Wth = (us*)(st + 3801088);
    us* Wtl = (us*)(st + 3932160);
    float* inv_gi  = (float*)(st + 4063232);
    float* inv_gt  = (float*)(st + 4063744);
    float* g_simbf = (float*)(st + 4064256);
    float* pm_row  = (float*)(st + 4194304);   // 512 KB (4 partials/row)
    float* ps_row  = (float*)(st + 4718592);   // 512 KB
    float* pm_col  = (float*)(st + 5242880);   // 512 KB
    float* ps_col  = (float*)(st + 5767168);   // 512 KB
    float* diag    = (float*)(st + 6291456);   // 128 KB
    us* patchesT   = (us*)(ws + 140640256);    // 33,554,432 B ([b][d][p])

    zero_out_k<<<1, 64, 0, stream>>>(out);
    convert_w_k<<<256, 256, 0, stream>>>(Wv, Wt, Wvh, Wvl, Wth, Wtl);

    // Global path (mean commutes with linear)
    mean_img_k<<<4096, 256, 0, stream>>>(img, mean_img);
    mean_text_s1<<<dim3(64, 8), 256, 0, stream>>>(text, textpart);
    mean_text_s2<<<64, 256, 0, stream>>>(textpart, mean_text);
    small_adapter_k<<<BB, 256, 0, stream>>>(mean_img, Wv, bv, mean_pat);
    small_adapter_k<<<BB, 256, 0, stream>>>(mean_pat, Wv, bv, g_img);
    small_adapter_k<<<BB, 256, 0, stream>>>(mean_text, Wt, bt, mean_tok);
    small_adapter_k<<<BB, 256, 0, stream>>>(mean_tok, Wt, bt, g_txt);
    inv_norm_f32_k<<<16, 256, 0, stream>>>(g_img, inv_gi);
    inv_norm_f32_k<<<16, 256, 0, stream>>>(g_txt, inv_gt);
    g_sim_k<<<64, 256, 0, stream>>>(g_img, g_txt, inv_gi, inv_gt, g_simbf);
    g_lse_k<<<128, 64, 0, stream>>>(g_simbf, out);

    // G1: patches = img.Wv + bv; NW=8 (R16)
    mfma_gemm<OPM_F32_COL, OPM_SPL_ROW, OUT_B16, 1, 256, 0, 8, 0><<<dim3(8, 1, BB), 512, 0, stream>>>(
        img, nullptr, Wvh, Wvl, patches,
        1024, 256, 256, 1024, 256, 256,
        1048576LL, 0LL, 524288LL, bv, nullptr, nullptr, 0.f, nullptr, nullptr,
        nullptr, nullptr, nullptr, nullptr, nullptr);

    // G2: tokens = text.Wt + bt; NW=8
    mfma_gemm<OPM_F32_ROW, OPM_SPL_ROW, OUT_B16, 1, 256, 0, 8, 0><<<dim3(4, 1, BB), 512, 0, stream>>>(
        text, nullptr, Wth, Wtl, tokens,
        512, 256, 256, 256, 256, 256,
        524288LL, 0LL, 262144LL, bt, nullptr, nullptr, 0.f, nullptr, nullptr,
        nullptr, nullptr, nullptr, nullptr, nullptr);

    // R17: patchesT = patches^T (enables DMA staging of G6's B operand)
    transpose_k<<<dim3(16, 4, BB), 256, 0, stream>>>(patches, patchesT);

    // G4': simT = tokens . patches^T, DMA-staged, row-minmax fused.
    mfma_gemm<OPM_B16_ROW, OPM_B16_ROW, OUT_B16, 3, 128, 0, 8, 1><<<dim3(4, 8, BB), 512, 0, stream>>>(
        tokens, nullptr, patches, nullptr, simT,
        512, 1024, 256, 256, 256, 1024,
        262144LL, 524288LL, 1048576LL, nullptr, nullptr, nullptr, 0.f, nullptr, nullptr,
        mnp, mxp, nullptr, nullptr, nullptr);

    minmax_merge_k<<<128, 256, 0, stream>>>(mnp, mxp, mnv, mxv);

    // G6: lgve = w.patches; R17 hybrid: A = simT reg-staged + weight
    // transform, B = patchesT DMA-staged (dbuf, counted vmcnt).
    mfma_gemm<OPM_WGT_ROW, OPM_B16_COL, OUT_B16, 0, 128, 0, 8, 2><<<dim3(4, 2, BB), 512, 0, stream>>>(
        simT, nullptr, patchesT, nullptr, lgve,
        512, 256, 1024, 1024, 1024, 256,
        1048576LL, 524288LL, 262144LL, nullptr, nullptr, nullptr, 0.f, mnv, mxv,
        nullptr, nullptr, nullptr, nullptr, nullptr);

    inv_norm_b16_k<<<8192, 256, 0, stream>>>(lgve, inv_l);
    inv_norm_b16_k<<<8192, 256, 0, stream>>>(tokens, inv_t);

    // G8: f_sim never materialized; DMA-staged, 4 row + 4 col LSE partials
    mfma_gemm<OPM_B16_ROW, OPM_B16_ROW, OUT_B16, 4, 128, 0, 8, 1><<<dim3(4, 4, BB), 512, 0, stream>>>(
        lgve, nullptr, tokens, nullptr, nullptr,
        512, 512, 256, 256, 256, 512,
        262144LL, 262144LL, 0LL, nullptr, inv_l, inv_t, TAU_INV, nullptr, nullptr,
        pm_row, ps_row, pm_col, ps_col, diag);

    fine_merge4_k<<<128, 256, 0, stream>>>(pm_row, ps_row, diag, out);
    fine_merge4_k<<<128, 256, 0, stream>>>(pm_col, ps_col, diag, out);
}